// Round 1
// baseline (5401.431 us; speedup 1.0000x reference)
//
#include <hip/hip_runtime.h>

// GCN: 2x GraphConv(128->128, norm='both') + ReLU, then Linear(128->16).
// N=100000 nodes, E=600000 edges, D=128, C=16.
//
// Pipeline (pointwise ops fused into GEMM prologues):
//   deg -> rs = rsqrt(max(deg,1))
//   t1 = (h * rs_out) @ W1
//   agg1 = scatter_add(t1[src] -> dst)
//   t2 = (relu(agg1 * rs_in + b1) * rs_out) @ W2
//   agg2 = scatter_add(t2[src] -> dst)
//   out = relu(agg2 * rs_in + b2) @ Wc + bc

__global__ __launch_bounds__(256) void deg_kernel(
    const int* __restrict__ src, const int* __restrict__ dst,
    float* __restrict__ deg, int E, int n)
{
    int i = blockIdx.x * blockDim.x + threadIdx.x;
    if (i < E) {
        atomicAdd(&deg[src[i]], 1.0f);       // out-degree
        atomicAdd(&deg[n + dst[i]], 1.0f);   // in-degree
    }
}

__global__ __launch_bounds__(256) void rsqrt_kernel(float* __restrict__ a, int m)
{
    int i = blockIdx.x * blockDim.x + threadIdx.x;
    if (i < m) a[i] = rsqrtf(fmaxf(a[i], 1.0f));
}

// C[n,128] = prologue(X)[n,128] @ W[128,128]
// MODE 0: prologue = X * rs_out[row]                               (layer 1)
// MODE 1: prologue = relu(X * rs_in[row] + bin[k]) * rs_out[row]   (layer 2)
// Tile: 64 rows x 128 cols, K staged in chunks of 32.
template <int MODE>
__global__ __launch_bounds__(256) void gemm128(
    const float* __restrict__ X, const float* __restrict__ W,
    const float* __restrict__ bin, const float* __restrict__ rs_out,
    const float* __restrict__ rs_in, float* __restrict__ Y, int n)
{
    __shared__ float xs[64][36];     // +4 pad keeps 16B alignment, rotates banks
    __shared__ float wsh[32][128];
    const int tid = threadIdx.x;
    const int row0 = blockIdx.x * 64;
    const int tx = tid & 31;         // col group: cols tx*4 .. tx*4+3
    const int ty = tid >> 5;         // row group: rows ty*8 .. ty*8+7

    float acc[8][4];
#pragma unroll
    for (int r = 0; r < 8; ++r) {
        acc[r][0] = acc[r][1] = acc[r][2] = acc[r][3] = 0.f;
    }

    for (int kc = 0; kc < 128; kc += 32) {
        // stage X chunk [64][32] with fused prologue
#pragma unroll
        for (int i0 = 0; i0 < 2; ++i0) {
            int i = tid + i0 * 256;
            int r = i >> 3, k4 = (i & 7) << 2;
            int row = row0 + r;
            float4 v = make_float4(0.f, 0.f, 0.f, 0.f);
            if (row < n) {
                v = *(const float4*)&X[(size_t)row * 128 + kc + k4];
                if (MODE == 0) {
                    float s = rs_out[row];
                    v.x *= s; v.y *= s; v.z *= s; v.w *= s;
                } else {
                    float si = rs_in[row], so = rs_out[row];
                    v.x = fmaxf(fmaf(v.x, si, bin[kc + k4 + 0]), 0.f) * so;
                    v.y = fmaxf(fmaf(v.y, si, bin[kc + k4 + 1]), 0.f) * so;
                    v.z = fmaxf(fmaf(v.z, si, bin[kc + k4 + 2]), 0.f) * so;
                    v.w = fmaxf(fmaf(v.w, si, bin[kc + k4 + 3]), 0.f) * so;
                }
            }
            *(float4*)&xs[r][k4] = v;
        }
        // stage W chunk [32][128]
#pragma unroll
        for (int i0 = 0; i0 < 4; ++i0) {
            int i = tid + i0 * 256;
            int k = i >> 5, j4 = (i & 31) << 2;
            *(float4*)&wsh[k][j4] = *(const float4*)&W[(size_t)(kc + k) * 128 + j4];
        }
        __syncthreads();
        for (int k = 0; k < 32; ++k) {
            float4 w = *(float4*)&wsh[k][tx << 2];
#pragma unroll
            for (int r = 0; r < 8; ++r) {
                float xv = xs[ty * 8 + r][k];   // broadcast within half-wave
                acc[r][0] = fmaf(xv, w.x, acc[r][0]);
                acc[r][1] = fmaf(xv, w.y, acc[r][1]);
                acc[r][2] = fmaf(xv, w.z, acc[r][2]);
                acc[r][3] = fmaf(xv, w.w, acc[r][3]);
            }
        }
        __syncthreads();
    }
#pragma unroll
    for (int r = 0; r < 8; ++r) {
        int row = row0 + ty * 8 + r;
        if (row < n) {
            float4 o = make_float4(acc[r][0], acc[r][1], acc[r][2], acc[r][3]);
            *(float4*)&Y[(size_t)row * 128 + (tx << 2)] = o;
        }
    }
}

// agg[dst] += T[src], 128 floats per edge. One thread per (edge, float4).
__global__ __launch_bounds__(256) void scatter_kernel(
    const float* __restrict__ T, const int* __restrict__ src,
    const int* __restrict__ dst, float* __restrict__ agg, int E)
{
    int gid = blockIdx.x * blockDim.x + threadIdx.x;
    int e = gid >> 5;
    if (e < E) {
        int c = (gid & 31) << 2;
        int s = src[e], d = dst[e];
        float4 v = *(const float4*)&T[(size_t)s * 128 + c];
        float* p = &agg[(size_t)d * 128 + c];
        atomicAdd(p + 0, v.x);
        atomicAdd(p + 1, v.y);
        atomicAdd(p + 2, v.z);
        atomicAdd(p + 3, v.w);
    }
}

// out[n,16] = relu(X * rs_in + b2) @ Wc + bc
__global__ __launch_bounds__(256) void classifier_kernel(
    const float* __restrict__ X, const float* __restrict__ Wc,
    const float* __restrict__ bin, const float* __restrict__ bout,
    const float* __restrict__ rs_in, float* __restrict__ out, int n)
{
    __shared__ float wl[128 * 16];
    __shared__ float xs[16][132];    // +4 pad
    const int tid = threadIdx.x;
    const int row0 = blockIdx.x * 16;
#pragma unroll
    for (int i0 = 0; i0 < 2; ++i0) {
        int i = tid + i0 * 256;
        ((float4*)wl)[i] = ((const float4*)Wc)[i];
    }
#pragma unroll
    for (int i0 = 0; i0 < 2; ++i0) {
        int i = tid + i0 * 256;
        int r = i >> 5, k4 = (i & 31) << 2;
        int row = row0 + r;
        float4 v = make_float4(0.f, 0.f, 0.f, 0.f);
        if (row < n) {
            v = *(const float4*)&X[(size_t)row * 128 + k4];
            float s = rs_in[row];
            v.x = fmaxf(fmaf(v.x, s, bin[k4 + 0]), 0.f);
            v.y = fmaxf(fmaf(v.y, s, bin[k4 + 1]), 0.f);
            v.z = fmaxf(fmaf(v.z, s, bin[k4 + 2]), 0.f);
            v.w = fmaxf(fmaf(v.w, s, bin[k4 + 3]), 0.f);
        }
        *(float4*)&xs[r][k4] = v;
    }
    __syncthreads();
    int c = tid & 15, r = tid >> 4;
    float acc = 0.f;
    for (int k = 0; k < 128; ++k) acc = fmaf(xs[r][k], wl[k * 16 + c], acc);
    int row = row0 + r;
    if (row < n) out[(size_t)row * 16 + c] = acc + bout[c];
}

extern "C" void kernel_launch(void* const* d_in, const int* in_sizes, int n_in,
                              void* d_out, int out_size, void* d_ws, size_t ws_size,
                              hipStream_t stream)
{
    const float* h   = (const float*)d_in[0];
    const int*   src = (const int*)d_in[1];
    const int*   dst = (const int*)d_in[2];
    const float* W1  = (const float*)d_in[3];
    const float* b1  = (const float*)d_in[4];
    const float* W2  = (const float*)d_in[5];
    const float* b2  = (const float*)d_in[6];
    const float* Wc  = (const float*)d_in[7];
    const float* bc  = (const float*)d_in[8];
    float* out = (float*)d_out;

    const int n = in_sizes[0] / 128;   // 100000
    const int E = in_sizes[1];         // 600000

    char* ws = (char*)d_ws;
    float* deg    = (float*)ws;        // [deg_out(n) | deg_in(n)] -> becomes rs_out/rs_in
    float* rs_out = deg;
    float* rs_in  = deg + n;
    size_t degBytes = ((size_t)2 * n * sizeof(float) + 255) & ~(size_t)255;
    float* bufA = (float*)(ws + degBytes);          // n*128 floats
    float* bufB = bufA + (size_t)n * 128;           // n*128 floats

    hipMemsetAsync(deg, 0, (size_t)2 * n * sizeof(float), stream);
    deg_kernel<<<(E + 255) / 256, 256, 0, stream>>>(src, dst, deg, E, n);
    rsqrt_kernel<<<(2 * n + 255) / 256, 256, 0, stream>>>(deg, 2 * n);

    int gblocks = (n + 63) / 64;

    // Layer 1
    gemm128<0><<<gblocks, 256, 0, stream>>>(h, W1, nullptr, rs_out, rs_in, bufA, n);
    hipMemsetAsync(bufB, 0, (size_t)n * 128 * sizeof(float), stream);
    scatter_kernel<<<(E * 32 + 255) / 256, 256, 0, stream>>>(bufA, src, dst, bufB, E);

    // Layer 2 (layer-1 epilogue fused into prologue)
    gemm128<1><<<gblocks, 256, 0, stream>>>(bufB, W2, b1, rs_out, rs_in, bufA, n);
    hipMemsetAsync(bufB, 0, (size_t)n * 128 * sizeof(float), stream);
    scatter_kernel<<<(E * 32 + 255) / 256, 256, 0, stream>>>(bufA, src, dst, bufB, E);

    // Classifier (layer-2 epilogue fused into prologue)
    classifier_kernel<<<(n + 15) / 16, 256, 0, stream>>>(bufB, Wc, b2, bc, rs_in, out, n);
}

// Round 2
// 2244.975 us; speedup vs baseline: 2.4060x; 2.4060x over previous
//
#include <hip/hip_runtime.h>

// GCN: 2x GraphConv(128->128, norm='both') + ReLU, then Linear(128->16).
// N=100000 nodes, E=600000 edges, D=128, C=16.
//
// Pipeline (pointwise ops fused into GEMM prologues):
//   deg -> rs = rsqrt(max(deg,1))
//   t1 = (h * rs_out) @ W1
//   agg1 = scatter_add(t1[src] -> dst)
//   t2 = (relu(agg1 * rs_in + b1) * rs_out) @ W2
//   agg2 = scatter_add(t2[src] -> dst)
//   out = relu(agg2 * rs_in + b2) @ Wc + bc

__global__ __launch_bounds__(256) void deg_kernel(
    const int* __restrict__ src, const int* __restrict__ dst,
    float* __restrict__ deg, int E, int n)
{
    int i = blockIdx.x * blockDim.x + threadIdx.x;
    if (i < E) {
        atomicAdd(&deg[src[i]], 1.0f);       // out-degree
        atomicAdd(&deg[n + dst[i]], 1.0f);   // in-degree
    }
}

__global__ __launch_bounds__(256) void rsqrt_kernel(float* __restrict__ a, int m)
{
    int i = blockIdx.x * blockDim.x + threadIdx.x;
    if (i < m) a[i] = rsqrtf(fmaxf(a[i], 1.0f));
}

// C[n,128] = prologue(X)[n,128] @ W[128,128]
// MODE 0: prologue = X * rs_out[row]                               (layer 1)
// MODE 1: prologue = relu(X * rs_in[row] + bin[k]) * rs_out[row]   (layer 2)
// Tile: 64 rows x 128 cols, K staged in chunks of 32.
// __launch_bounds__(256,4): cap at ~128 VGPR so the allocator cannot blow
// past occupancy; unroll-4 on the k-loop bounds LDS-load hoisting liveness
// (round-1 full unroll spilled acc -> 3.7 GB scratch traffic).
template <int MODE>
__global__ __launch_bounds__(256, 4) void gemm128(
    const float* __restrict__ X, const float* __restrict__ W,
    const float* __restrict__ bin, const float* __restrict__ rs_out,
    const float* __restrict__ rs_in, float* __restrict__ Y, int n)
{
    __shared__ float xs[64][36];     // +4 pad keeps 16B alignment, rotates banks
    __shared__ float wsh[32][128];
    const int tid = threadIdx.x;
    const int row0 = blockIdx.x * 64;
    const int tx = tid & 31;         // col group: cols tx*4 .. tx*4+3
    const int ty = tid >> 5;         // row group: rows ty*8 .. ty*8+7

    float acc[8][4];
#pragma unroll
    for (int r = 0; r < 8; ++r) {
        acc[r][0] = acc[r][1] = acc[r][2] = acc[r][3] = 0.f;
    }

    for (int kc = 0; kc < 128; kc += 32) {
        // stage X chunk [64][32] with fused prologue
#pragma unroll
        for (int i0 = 0; i0 < 2; ++i0) {
            int i = tid + i0 * 256;
            int r = i >> 3, k4 = (i & 7) << 2;
            int row = row0 + r;
            float4 v = make_float4(0.f, 0.f, 0.f, 0.f);
            if (row < n) {
                v = *(const float4*)&X[(size_t)row * 128 + kc + k4];
                if (MODE == 0) {
                    float s = rs_out[row];
                    v.x *= s; v.y *= s; v.z *= s; v.w *= s;
                } else {
                    float si = rs_in[row], so = rs_out[row];
                    v.x = fmaxf(fmaf(v.x, si, bin[kc + k4 + 0]), 0.f) * so;
                    v.y = fmaxf(fmaf(v.y, si, bin[kc + k4 + 1]), 0.f) * so;
                    v.z = fmaxf(fmaf(v.z, si, bin[kc + k4 + 2]), 0.f) * so;
                    v.w = fmaxf(fmaf(v.w, si, bin[kc + k4 + 3]), 0.f) * so;
                }
            }
            *(float4*)&xs[r][k4] = v;
        }
        // stage W chunk [32][128]
#pragma unroll
        for (int i0 = 0; i0 < 4; ++i0) {
            int i = tid + i0 * 256;
            int k = i >> 5, j4 = (i & 31) << 2;
            *(float4*)&wsh[k][j4] = *(const float4*)&W[(size_t)(kc + k) * 128 + j4];
        }
        __syncthreads();
        // bounded-liveness inner loop: per k, one float4 w + 8 xs broadcasts
#pragma unroll 4
        for (int k = 0; k < 32; ++k) {
            float4 w = *(float4*)&wsh[k][tx << 2];
#pragma unroll
            for (int r = 0; r < 8; ++r) {
                float xv = xs[ty * 8 + r][k];   // same addr across 32 lanes: broadcast
                acc[r][0] = fmaf(xv, w.x, acc[r][0]);
                acc[r][1] = fmaf(xv, w.y, acc[r][1]);
                acc[r][2] = fmaf(xv, w.z, acc[r][2]);
                acc[r][3] = fmaf(xv, w.w, acc[r][3]);
            }
        }
        __syncthreads();
    }
#pragma unroll
    for (int r = 0; r < 8; ++r) {
        int row = row0 + ty * 8 + r;
        if (row < n) {
            float4 o = make_float4(acc[r][0], acc[r][1], acc[r][2], acc[r][3]);
            *(float4*)&Y[(size_t)row * 128 + (tx << 2)] = o;
        }
    }
}

// agg[dst] += T[src], 128 floats per edge. One thread per (edge, float4).
__global__ __launch_bounds__(256) void scatter_kernel(
    const float* __restrict__ T, const int* __restrict__ src,
    const int* __restrict__ dst, float* __restrict__ agg, int E)
{
    int gid = blockIdx.x * blockDim.x + threadIdx.x;
    int e = gid >> 5;
    if (e < E) {
        int c = (gid & 31) << 2;
        int s = src[e], d = dst[e];
        float4 v = *(const float4*)&T[(size_t)s * 128 + c];
        float* p = &agg[(size_t)d * 128 + c];
        atomicAdd(p + 0, v.x);
        atomicAdd(p + 1, v.y);
        atomicAdd(p + 2, v.z);
        atomicAdd(p + 3, v.w);
    }
}

// out[n,16] = relu(X * rs_in + b2) @ Wc + bc
__global__ __launch_bounds__(256) void classifier_kernel(
    const float* __restrict__ X, const float* __restrict__ Wc,
    const float* __restrict__ bin, const float* __restrict__ bout,
    const float* __restrict__ rs_in, float* __restrict__ out, int n)
{
    __shared__ float wl[128 * 16];
    __shared__ float xs[16][132];    // +4 pad
    const int tid = threadIdx.x;
    const int row0 = blockIdx.x * 16;
#pragma unroll
    for (int i0 = 0; i0 < 2; ++i0) {
        int i = tid + i0 * 256;
        ((float4*)wl)[i] = ((const float4*)Wc)[i];
    }
#pragma unroll
    for (int i0 = 0; i0 < 2; ++i0) {
        int i = tid + i0 * 256;
        int r = i >> 5, k4 = (i & 31) << 2;
        int row = row0 + r;
        float4 v = make_float4(0.f, 0.f, 0.f, 0.f);
        if (row < n) {
            v = *(const float4*)&X[(size_t)row * 128 + k4];
            float s = rs_in[row];
            v.x = fmaxf(fmaf(v.x, s, bin[k4 + 0]), 0.f);
            v.y = fmaxf(fmaf(v.y, s, bin[k4 + 1]), 0.f);
            v.z = fmaxf(fmaf(v.z, s, bin[k4 + 2]), 0.f);
            v.w = fmaxf(fmaf(v.w, s, bin[k4 + 3]), 0.f);
        }
        *(float4*)&xs[r][k4] = v;
    }
    __syncthreads();
    int c = tid & 15, r = tid >> 4;
    float acc = 0.f;
#pragma unroll 8
    for (int k = 0; k < 128; ++k) acc = fmaf(xs[r][k], wl[k * 16 + c], acc);
    int row = row0 + r;
    if (row < n) out[(size_t)row * 16 + c] = acc + bout[c];
}

extern "C" void kernel_launch(void* const* d_in, const int* in_sizes, int n_in,
                              void* d_out, int out_size, void* d_ws, size_t ws_size,
                              hipStream_t stream)
{
    const float* h   = (const float*)d_in[0];
    const int*   src = (const int*)d_in[1];
    const int*   dst = (const int*)d_in[2];
    const float* W1  = (const float*)d_in[3];
    const float* b1  = (const float*)d_in[4];
    const float* W2  = (const float*)d_in[5];
    const float* b2  = (const float*)d_in[6];
    const float* Wc  = (const float*)d_in[7];
    const float* bc  = (const float*)d_in[8];
    float* out = (float*)d_out;

    const int n = in_sizes[0] / 128;   // 100000
    const int E = in_sizes[1];         // 600000

    char* ws = (char*)d_ws;
    float* deg    = (float*)ws;        // [deg_out(n) | deg_in(n)] -> becomes rs_out/rs_in
    float* rs_out = deg;
    float* rs_in  = deg + n;
    size_t degBytes = ((size_t)2 * n * sizeof(float) + 255) & ~(size_t)255;
    float* bufA = (float*)(ws + degBytes);          // n*128 floats
    float* bufB = bufA + (size_t)n * 128;           // n*128 floats

    hipMemsetAsync(deg, 0, (size_t)2 * n * sizeof(float), stream);
    deg_kernel<<<(E + 255) / 256, 256, 0, stream>>>(src, dst, deg, E, n);
    rsqrt_kernel<<<(2 * n + 255) / 256, 256, 0, stream>>>(deg, 2 * n);

    int gblocks = (n + 63) / 64;

    // Layer 1
    gemm128<0><<<gblocks, 256, 0, stream>>>(h, W1, nullptr, rs_out, rs_in, bufA, n);
    hipMemsetAsync(bufB, 0, (size_t)n * 128 * sizeof(float), stream);
    scatter_kernel<<<(E * 32 + 255) / 256, 256, 0, stream>>>(bufA, src, dst, bufB, E);

    // Layer 2 (layer-1 epilogue fused into prologue)
    gemm128<1><<<gblocks, 256, 0, stream>>>(bufB, W2, b1, rs_out, rs_in, bufA, n);
    hipMemsetAsync(bufB, 0, (size_t)n * 128 * sizeof(float), stream);
    scatter_kernel<<<(E * 32 + 255) / 256, 256, 0, stream>>>(bufA, src, dst, bufB, E);

    // Classifier (layer-2 epilogue fused into prologue)
    classifier_kernel<<<(n + 15) / 16, 256, 0, stream>>>(bufB, Wc, b2, bc, rs_in, out, n);
}

// Round 3
// 325.119 us; speedup vs baseline: 16.6137x; 6.9051x over previous
//
#include <hip/hip_runtime.h>

// GCN: 2x GraphConv(128->128, norm='both') + ReLU, then Linear(128->16).
// N=100000 nodes, E=600000 edges, D=128, C=16.
//
// Round 3: atomic scatter (1016 us, 1.2 GB atomic write traffic) replaced by
// per-call CSR (histogram -> scan -> fill) + deterministic per-node gather.
//
// Pipeline:
//   cnt_out/cnt_in = histogram(src/dst); rs = rsqrt(max(cnt,1))
//   CSR: starts = exclusive_scan(cnt_in); eidx[cursor[dst[e]]++] = src[e]
//   t1 = (h * rs_out) @ W1
//   agg1[d] = sum_{e: dst=d} t1[src[e]]        (gather, no atomics)
//   t2 = (relu(agg1 * rs_in + b1) * rs_out) @ W2
//   agg2 = gather(t2)
//   out = relu(agg2 * rs_in + b2) @ Wc + bc

__global__ __launch_bounds__(256) void count_kernel(
    const int* __restrict__ src, const int* __restrict__ dst,
    int* __restrict__ cnt_out, int* __restrict__ cnt_in, int E)
{
    int i = blockIdx.x * blockDim.x + threadIdx.x;
    if (i < E) {
        atomicAdd(&cnt_out[src[i]], 1);
        atomicAdd(&cnt_in[dst[i]], 1);
    }
}

// rs[i] = rsqrt(max(cnt[i],1)) over both degree arrays at once (contiguous)
__global__ __launch_bounds__(256) void rs_kernel(
    const int* __restrict__ cnt, float* __restrict__ rs, int m)
{
    int i = blockIdx.x * blockDim.x + threadIdx.x;
    if (i < m) rs[i] = rsqrtf(fmaxf((float)cnt[i], 1.0f));
}

// exclusive scan, 3-phase: per-block scan -> scan block sums -> add offsets
__global__ __launch_bounds__(256) void scan1_kernel(
    const int* __restrict__ cnt, int* __restrict__ excl,
    int* __restrict__ bsum, int n)
{
    __shared__ int tmp[256];
    int i = blockIdx.x * 256 + threadIdx.x;
    int v = (i < n) ? cnt[i] : 0;
    tmp[threadIdx.x] = v;
    __syncthreads();
    for (int off = 1; off < 256; off <<= 1) {
        int t = (threadIdx.x >= off) ? tmp[threadIdx.x - off] : 0;
        __syncthreads();
        tmp[threadIdx.x] += t;
        __syncthreads();
    }
    if (i < n) excl[i] = tmp[threadIdx.x] - v;
    if (threadIdx.x == 255) bsum[blockIdx.x] = tmp[255];
}

__global__ __launch_bounds__(1024) void scan2_kernel(int* __restrict__ bsum, int nb)
{
    __shared__ int tmp[1024];
    int t = threadIdx.x;
    int v = (t < nb) ? bsum[t] : 0;
    tmp[t] = v;
    __syncthreads();
    for (int off = 1; off < 1024; off <<= 1) {
        int x = (t >= off) ? tmp[t - off] : 0;
        __syncthreads();
        tmp[t] += x;
        __syncthreads();
    }
    if (t < nb) bsum[t] = tmp[t] - v;   // exclusive
}

__global__ __launch_bounds__(256) void scan3_kernel(
    int* __restrict__ excl, const int* __restrict__ bsum, int n)
{
    int i = blockIdx.x * 256 + threadIdx.x;
    if (i < n) excl[i] += bsum[blockIdx.x];
}

__global__ __launch_bounds__(256) void fill_kernel(
    const int* __restrict__ src, const int* __restrict__ dst,
    int* __restrict__ cursor, int* __restrict__ eidx, int E)
{
    int e = blockIdx.x * blockDim.x + threadIdx.x;
    if (e < E) {
        int p = atomicAdd(&cursor[dst[e]], 1);
        eidx[p] = src[e];
    }
}

// agg[d][:] = sum over in-edges of T[src][:]. One 64-lane wave per node,
// float2 per lane = one coalesced 512 B row read per edge. 2-edge unroll
// breaks the load->add dependency chain.
__global__ __launch_bounds__(256) void gather_agg(
    const float* __restrict__ T, const int* __restrict__ eidx,
    const int* __restrict__ starts, float* __restrict__ agg, int n, int E)
{
    int wid = (blockIdx.x * 256 + threadIdx.x) >> 6;
    int lane = threadIdx.x & 63;
    if (wid >= n) return;
    int s0 = starts[wid];
    int s1 = (wid + 1 < n) ? starts[wid + 1] : E;
    float2 acc = make_float2(0.f, 0.f);
    int j = s0;
    for (; j + 1 < s1; j += 2) {
        int sA = eidx[j], sB = eidx[j + 1];
        float2 a = *(const float2*)&T[(size_t)sA * 128 + lane * 2];
        float2 b = *(const float2*)&T[(size_t)sB * 128 + lane * 2];
        acc.x += a.x + b.x;
        acc.y += a.y + b.y;
    }
    if (j < s1) {
        int sA = eidx[j];
        float2 a = *(const float2*)&T[(size_t)sA * 128 + lane * 2];
        acc.x += a.x;
        acc.y += a.y;
    }
    *(float2*)&agg[(size_t)wid * 128 + lane * 2] = acc;
}

// C[n,128] = prologue(X)[n,128] @ W[128,128]
// MODE 0: prologue = X * rs_out[row]                               (layer 1)
// MODE 1: prologue = relu(X * rs_in[row] + bin[k]) * rs_out[row]   (layer 2)
template <int MODE>
__global__ __launch_bounds__(256, 4) void gemm128(
    const float* __restrict__ X, const float* __restrict__ W,
    const float* __restrict__ bin, const float* __restrict__ rs_out,
    const float* __restrict__ rs_in, float* __restrict__ Y, int n)
{
    __shared__ float xs[64][36];
    __shared__ float wsh[32][128];
    const int tid = threadIdx.x;
    const int row0 = blockIdx.x * 64;
    const int tx = tid & 31;
    const int ty = tid >> 5;

    float acc[8][4];
#pragma unroll
    for (int r = 0; r < 8; ++r) {
        acc[r][0] = acc[r][1] = acc[r][2] = acc[r][3] = 0.f;
    }

    for (int kc = 0; kc < 128; kc += 32) {
#pragma unroll
        for (int i0 = 0; i0 < 2; ++i0) {
            int i = tid + i0 * 256;
            int r = i >> 3, k4 = (i & 7) << 2;
            int row = row0 + r;
            float4 v = make_float4(0.f, 0.f, 0.f, 0.f);
            if (row < n) {
                v = *(const float4*)&X[(size_t)row * 128 + kc + k4];
                if (MODE == 0) {
                    float s = rs_out[row];
                    v.x *= s; v.y *= s; v.z *= s; v.w *= s;
                } else {
                    float si = rs_in[row], so = rs_out[row];
                    v.x = fmaxf(fmaf(v.x, si, bin[kc + k4 + 0]), 0.f) * so;
                    v.y = fmaxf(fmaf(v.y, si, bin[kc + k4 + 1]), 0.f) * so;
                    v.z = fmaxf(fmaf(v.z, si, bin[kc + k4 + 2]), 0.f) * so;
                    v.w = fmaxf(fmaf(v.w, si, bin[kc + k4 + 3]), 0.f) * so;
                }
            }
            *(float4*)&xs[r][k4] = v;
        }
#pragma unroll
        for (int i0 = 0; i0 < 4; ++i0) {
            int i = tid + i0 * 256;
            int k = i >> 5, j4 = (i & 31) << 2;
            *(float4*)&wsh[k][j4] = *(const float4*)&W[(size_t)(kc + k) * 128 + j4];
        }
        __syncthreads();
#pragma unroll 4
        for (int k = 0; k < 32; ++k) {
            float4 w = *(float4*)&wsh[k][tx << 2];
#pragma unroll
            for (int r = 0; r < 8; ++r) {
                float xv = xs[ty * 8 + r][k];
                acc[r][0] = fmaf(xv, w.x, acc[r][0]);
                acc[r][1] = fmaf(xv, w.y, acc[r][1]);
                acc[r][2] = fmaf(xv, w.z, acc[r][2]);
                acc[r][3] = fmaf(xv, w.w, acc[r][3]);
            }
        }
        __syncthreads();
    }
#pragma unroll
    for (int r = 0; r < 8; ++r) {
        int row = row0 + ty * 8 + r;
        if (row < n) {
            float4 o = make_float4(acc[r][0], acc[r][1], acc[r][2], acc[r][3]);
            *(float4*)&Y[(size_t)row * 128 + (tx << 2)] = o;
        }
    }
}

// out[n,16] = relu(X * rs_in + b2) @ Wc + bc
__global__ __launch_bounds__(256) void classifier_kernel(
    const float* __restrict__ X, const float* __restrict__ Wc,
    const float* __restrict__ bin, const float* __restrict__ bout,
    const float* __restrict__ rs_in, float* __restrict__ out, int n)
{
    __shared__ float wl[128 * 16];
    __shared__ float xs[16][132];
    const int tid = threadIdx.x;
    const int row0 = blockIdx.x * 16;
#pragma unroll
    for (int i0 = 0; i0 < 2; ++i0) {
        int i = tid + i0 * 256;
        ((float4*)wl)[i] = ((const float4*)Wc)[i];
    }
#pragma unroll
    for (int i0 = 0; i0 < 2; ++i0) {
        int i = tid + i0 * 256;
        int r = i >> 5, k4 = (i & 31) << 2;
        int row = row0 + r;
        float4 v = make_float4(0.f, 0.f, 0.f, 0.f);
        if (row < n) {
            v = *(const float4*)&X[(size_t)row * 128 + k4];
            float s = rs_in[row];
            v.x = fmaxf(fmaf(v.x, s, bin[k4 + 0]), 0.f);
            v.y = fmaxf(fmaf(v.y, s, bin[k4 + 1]), 0.f);
            v.z = fmaxf(fmaf(v.z, s, bin[k4 + 2]), 0.f);
            v.w = fmaxf(fmaf(v.w, s, bin[k4 + 3]), 0.f);
        }
        *(float4*)&xs[r][k4] = v;
    }
    __syncthreads();
    int c = tid & 15, r = tid >> 4;
    float acc = 0.f;
#pragma unroll 8
    for (int k = 0; k < 128; ++k) acc = fmaf(xs[r][k], wl[k * 16 + c], acc);
    int row = row0 + r;
    if (row < n) out[(size_t)row * 16 + c] = acc + bout[c];
}

extern "C" void kernel_launch(void* const* d_in, const int* in_sizes, int n_in,
                              void* d_out, int out_size, void* d_ws, size_t ws_size,
                              hipStream_t stream)
{
    const float* h   = (const float*)d_in[0];
    const int*   src = (const int*)d_in[1];
    const int*   dst = (const int*)d_in[2];
    const float* W1  = (const float*)d_in[3];
    const float* b1  = (const float*)d_in[4];
    const float* W2  = (const float*)d_in[5];
    const float* b2  = (const float*)d_in[6];
    const float* Wc  = (const float*)d_in[7];
    const float* bc  = (const float*)d_in[8];
    float* out = (float*)d_out;

    const int n = in_sizes[0] / 128;   // 100000
    const int E = in_sizes[1];         // 600000
    const int nb = (n + 255) / 256;    // scan blocks (391, must be <= 1024)

    char* ws = (char*)d_ws;
    int*   cnt_out = (int*)ws;                     // n
    int*   cnt_in  = cnt_out + n;                  // n (contiguous with cnt_out)
    float* rs_out  = (float*)(cnt_in + n);         // n
    float* rs_in   = rs_out + n;                   // n (contiguous with rs_out)
    int*   starts  = (int*)(rs_in + n);            // n
    int*   cursor  = starts + n;                   // n
    int*   bsum    = cursor + n;                   // 1024
    int*   eidx    = bsum + 1024;                  // E
    size_t off = ((size_t)((char*)(eidx + E) - ws) + 255) & ~(size_t)255;
    float* bufA = (float*)(ws + off);              // n*128
    float* bufB = bufA + (size_t)n * 128;          // n*128

    // degrees + CSR build
    hipMemsetAsync(cnt_out, 0, (size_t)2 * n * sizeof(int), stream);
    count_kernel<<<(E + 255) / 256, 256, 0, stream>>>(src, dst, cnt_out, cnt_in, E);
    rs_kernel<<<(2 * n + 255) / 256, 256, 0, stream>>>(cnt_out, rs_out, 2 * n);
    scan1_kernel<<<nb, 256, 0, stream>>>(cnt_in, starts, bsum, n);
    scan2_kernel<<<1, 1024, 0, stream>>>(bsum, nb);
    scan3_kernel<<<nb, 256, 0, stream>>>(starts, bsum, n);
    hipMemcpyAsync(cursor, starts, (size_t)n * sizeof(int),
                   hipMemcpyDeviceToDevice, stream);
    fill_kernel<<<(E + 255) / 256, 256, 0, stream>>>(src, dst, cursor, eidx, E);

    int gblocks = (n + 63) / 64;
    int ablocks = (n + 3) / 4;   // 4 waves/block, 1 wave/node

    // Layer 1
    gemm128<0><<<gblocks, 256, 0, stream>>>(h, W1, nullptr, rs_out, rs_in, bufA, n);
    gather_agg<<<ablocks, 256, 0, stream>>>(bufA, eidx, starts, bufB, n, E);

    // Layer 2 (layer-1 epilogue fused into gemm prologue)
    gemm128<1><<<gblocks, 256, 0, stream>>>(bufB, W2, b1, rs_out, rs_in, bufA, n);
    gather_agg<<<ablocks, 256, 0, stream>>>(bufA, eidx, starts, bufB, n, E);

    // Classifier (layer-2 epilogue fused into prologue)
    classifier_kernel<<<(n + 15) / 16, 256, 0, stream>>>(bufB, Wc, b2, bc, rs_in, out, n);
}

// Round 4
// 306.254 us; speedup vs baseline: 17.6371x; 1.0616x over previous
//
#include <hip/hip_runtime.h>

// GCN: 2x GraphConv(128->128, norm='both') + ReLU, then Linear(128->16).
// N=100000, E=600000, D=128, C=16.
//
// Round 4: fp16 intermediates + MFMA (v_mfma_f32_32x32x8f16, fp32 accum),
// gather fused with layer epilogue/prologue, no-LDS GEMM (W pre-transposed
// to f16 WT[n][k], L2-resident; X frags read once per block).
//
//   cnt_out/in = histogram(src/dst); rs = rsqrt(max(cnt,1))
//   CSR: starts = exclscan(cnt_in); eidx[cursor[dst[e]]++] = src[e]
//   T1  = (h * rs_out) @ W1                          (fp16 out)
//   X2  = f16( relu(gather(T1) * rs_in + b1) * rs_out )
//   T2  = X2 @ W2                                    (fp16 out)
//   X3  = f16( relu(gather(T2) * rs_in + b2) )
//   out = X3 @ Wc + bc                               (fp32)

typedef __attribute__((ext_vector_type(4))) _Float16 half4_t;
typedef __attribute__((ext_vector_type(2))) _Float16 half2_t;
typedef __attribute__((ext_vector_type(16))) float floatx16;

__global__ __launch_bounds__(256) void count_kernel(
    const int* __restrict__ src, const int* __restrict__ dst,
    int* __restrict__ cnt_out, int* __restrict__ cnt_in, int E)
{
    int i = blockIdx.x * blockDim.x + threadIdx.x;
    if (i < E) {
        atomicAdd(&cnt_out[src[i]], 1);
        atomicAdd(&cnt_in[dst[i]], 1);
    }
}

__global__ __launch_bounds__(256) void rs_kernel(
    const int* __restrict__ cnt, float* __restrict__ rs, int m)
{
    int i = blockIdx.x * blockDim.x + threadIdx.x;
    if (i < m) rs[i] = rsqrtf(fmaxf((float)cnt[i], 1.0f));
}

__global__ __launch_bounds__(256) void scan1_kernel(
    const int* __restrict__ cnt, int* __restrict__ excl,
    int* __restrict__ bsum, int n)
{
    __shared__ int tmp[256];
    int i = blockIdx.x * 256 + threadIdx.x;
    int v = (i < n) ? cnt[i] : 0;
    tmp[threadIdx.x] = v;
    __syncthreads();
    for (int off = 1; off < 256; off <<= 1) {
        int t = (threadIdx.x >= off) ? tmp[threadIdx.x - off] : 0;
        __syncthreads();
        tmp[threadIdx.x] += t;
        __syncthreads();
    }
    if (i < n) excl[i] = tmp[threadIdx.x] - v;
    if (threadIdx.x == 255) bsum[blockIdx.x] = tmp[255];
}

__global__ __launch_bounds__(1024) void scan2_kernel(int* __restrict__ bsum, int nb)
{
    __shared__ int tmp[1024];
    int t = threadIdx.x;
    int v = (t < nb) ? bsum[t] : 0;
    tmp[t] = v;
    __syncthreads();
    for (int off = 1; off < 1024; off <<= 1) {
        int x = (t >= off) ? tmp[t - off] : 0;
        __syncthreads();
        tmp[t] += x;
        __syncthreads();
    }
    if (t < nb) bsum[t] = tmp[t] - v;   // exclusive
}

// adds block offsets; writes BOTH starts and cursor (saves a d2d copy)
__global__ __launch_bounds__(256) void scan3_kernel(
    int* __restrict__ excl, int* __restrict__ cursor,
    const int* __restrict__ bsum, int n)
{
    int i = blockIdx.x * 256 + threadIdx.x;
    if (i < n) {
        int v = excl[i] + bsum[blockIdx.x];
        excl[i] = v;
        cursor[i] = v;
    }
}

__global__ __launch_bounds__(256) void fill_kernel(
    const int* __restrict__ src, const int* __restrict__ dst,
    int* __restrict__ cursor, int* __restrict__ eidx, int E)
{
    int e = blockIdx.x * blockDim.x + threadIdx.x;
    if (e < E) {
        int p = atomicAdd(&cursor[dst[e]], 1);
        eidx[p] = src[e];
    }
}

// WT[j] = W[(j&127)*128 + (j>>7)]  (f16 transpose; coalesced writes)
__global__ __launch_bounds__(256) void wt_kernel(
    const float* __restrict__ W1, const float* __restrict__ W2,
    _Float16* __restrict__ WT1, _Float16* __restrict__ WT2)
{
    int gid = blockIdx.x * 256 + threadIdx.x;      // 0..32767
    int j = gid & 16383;
    float v = (gid < 16384) ? W1[(j & 127) * 128 + (j >> 7)]
                            : W2[(j & 127) * 128 + (j >> 7)];
    if (gid < 16384) WT1[j] = (_Float16)v;
    else             WT2[j] = (_Float16)v;
}

// T[n][128] f16 = prologue(X) @ W  via v_mfma_f32_32x32x8f16 (fp32 accum).
// Block = 4 waves; wave w: rows [blk*128 + w*32, +32), all 128 cols (4 n-tiles).
// A-frag: lane l holds X[row0+(l&31)][kt*8+(l>>5)*4 .. +3]
// B-frag: lane l holds WT[nt*32+(l&31)][kt*8+(l>>5)*4 .. +3]   (WT[n][k] = W[k][n])
// D:      col = nt*32+(l&31), row = row0 + (reg&3)+8*(reg>>2)+4*(l>>5)
// MODE 0: X fp32, A = X*rs_out[row].  MODE 1: X f16, A = X.
template <int MODE>
__global__ __launch_bounds__(256) void gemm_mfma(
    const void* __restrict__ Xv, const _Float16* __restrict__ WT,
    const float* __restrict__ rs_out, _Float16* __restrict__ T, int n)
{
    const int lane = threadIdx.x & 63;
    const int wv   = threadIdx.x >> 6;
    const int m    = lane & 31;
    const int g    = lane >> 5;
    const int rbase = blockIdx.x * 128 + wv * 32;
    const int row  = rbase + m;
    const bool rowok = row < n;
    const int rclamp = rowok ? row : 0;

    floatx16 acc0 = {}, acc1 = {}, acc2 = {}, acc3 = {};
    const _Float16* wtp = WT + (size_t)m * 128 + g * 4;

    if (MODE == 0) {
        const float* X = (const float*)Xv;
        const float scale = rowok ? rs_out[row] : 0.0f;
        const float* xp = X + (size_t)rclamp * 128 + g * 4;
#pragma unroll 2
        for (int kt = 0; kt < 16; ++kt) {
            float4 xv = *(const float4*)(xp + kt * 8);
            half4_t a;
            a[0] = (_Float16)(xv.x * scale);
            a[1] = (_Float16)(xv.y * scale);
            a[2] = (_Float16)(xv.z * scale);
            a[3] = (_Float16)(xv.w * scale);
            const _Float16* wk = wtp + kt * 8;
            half4_t b0 = *(const half4_t*)(wk);
            half4_t b1 = *(const half4_t*)(wk + 32 * 128);
            half4_t b2 = *(const half4_t*)(wk + 64 * 128);
            half4_t b3 = *(const half4_t*)(wk + 96 * 128);
            acc0 = __builtin_amdgcn_mfma_f32_32x32x8f16(a, b0, acc0, 0, 0, 0);
            acc1 = __builtin_amdgcn_mfma_f32_32x32x8f16(a, b1, acc1, 0, 0, 0);
            acc2 = __builtin_amdgcn_mfma_f32_32x32x8f16(a, b2, acc2, 0, 0, 0);
            acc3 = __builtin_amdgcn_mfma_f32_32x32x8f16(a, b3, acc3, 0, 0, 0);
        }
    } else {
        const _Float16* X = (const _Float16*)Xv;
        const _Float16* xp = X + (size_t)rclamp * 128 + g * 4;
#pragma unroll 2
        for (int kt = 0; kt < 16; ++kt) {
            half4_t a = *(const half4_t*)(xp + kt * 8);
            const _Float16* wk = wtp + kt * 8;
            half4_t b0 = *(const half4_t*)(wk);
            half4_t b1 = *(const half4_t*)(wk + 32 * 128);
            half4_t b2 = *(const half4_t*)(wk + 64 * 128);
            half4_t b3 = *(const half4_t*)(wk + 96 * 128);
            acc0 = __builtin_amdgcn_mfma_f32_32x32x8f16(a, b0, acc0, 0, 0, 0);
            acc1 = __builtin_amdgcn_mfma_f32_32x32x8f16(a, b1, acc1, 0, 0, 0);
            acc2 = __builtin_amdgcn_mfma_f32_32x32x8f16(a, b2, acc2, 0, 0, 0);
            acc3 = __builtin_amdgcn_mfma_f32_32x32x8f16(a, b3, acc3, 0, 0, 0);
        }
    }

#pragma unroll
    for (int rg = 0; rg < 16; ++rg) {
        int rd = (rg & 3) + 8 * (rg >> 2) + 4 * g;
        int orow = rbase + rd;
        if (orow < n) {
            _Float16* tp = T + (size_t)orow * 128 + m;
            tp[0]  = (_Float16)acc0[rg];
            tp[32] = (_Float16)acc1[rg];
            tp[64] = (_Float16)acc2[rg];
            tp[96] = (_Float16)acc3[rg];
        }
    }
}

// Xout[d][:] = epilogue( sum_{in-edges} T[src][:] ), one 64-lane wave per node.
// Lane handles 2 halves (dword per edge). fp32 accumulate, 2-edge unroll.
// MODE 0: epi = f16(relu(acc*rs_in + b)*rs_out)   MODE 1: epi = f16(relu(acc*rs_in + b))
template <int MODE>
__global__ __launch_bounds__(256) void gather_f16(
    const _Float16* __restrict__ T, const int* __restrict__ eidx,
    const int* __restrict__ starts, const float* __restrict__ rs_in,
    const float* __restrict__ rs_out, const float* __restrict__ bias,
    _Float16* __restrict__ Xout, int n, int E)
{
    int wid = (blockIdx.x * 256 + threadIdx.x) >> 6;
    int lane = threadIdx.x & 63;
    if (wid >= n) return;
    int s0 = starts[wid];
    int s1 = (wid + 1 < n) ? starts[wid + 1] : E;
    float a0 = 0.f, a1 = 0.f, b0 = 0.f, b1 = 0.f;
    int j = s0;
    for (; j + 1 < s1; j += 2) {
        int sA = eidx[j], sB = eidx[j + 1];
        half2_t va = *(const half2_t*)&T[(size_t)sA * 128 + lane * 2];
        half2_t vb = *(const half2_t*)&T[(size_t)sB * 128 + lane * 2];
        a0 += (float)va[0]; a1 += (float)va[1];
        b0 += (float)vb[0]; b1 += (float)vb[1];
    }
    if (j < s1) {
        int sA = eidx[j];
        half2_t va = *(const half2_t*)&T[(size_t)sA * 128 + lane * 2];
        a0 += (float)va[0]; a1 += (float)va[1];
    }
    float ri = rs_in[wid];
    float x0 = fmaxf(fmaf(a0 + b0, ri, bias[lane * 2 + 0]), 0.f);
    float x1 = fmaxf(fmaf(a1 + b1, ri, bias[lane * 2 + 1]), 0.f);
    if (MODE == 0) {
        float ro = rs_out[wid];
        x0 *= ro; x1 *= ro;
    }
    half2_t o;
    o[0] = (_Float16)x0;
    o[1] = (_Float16)x1;
    *(half2_t*)&Xout[(size_t)wid * 128 + lane * 2] = o;
}

// out[n,16] = X3 @ Wc + bc   (X3 f16 already has relu/bias applied)
__global__ __launch_bounds__(256) void classifier_kernel(
    const _Float16* __restrict__ X, const float* __restrict__ Wc,
    const float* __restrict__ bout, float* __restrict__ out, int n)
{
    __shared__ float wl[128 * 16];       // 8 KB
    __shared__ _Float16 xs[16][128];     // 4 KB
    const int tid = threadIdx.x;
    const int row0 = blockIdx.x * 16;
#pragma unroll
    for (int i0 = 0; i0 < 2; ++i0) {
        int i = tid + i0 * 256;
        ((float4*)wl)[i] = ((const float4*)Wc)[i];
    }
    {
        // 16 rows x 128 halves = 256 x 16B chunks, one per thread
        int r = tid >> 4, c8 = (tid & 15) * 8;
        int row = row0 + r;
        float4 v = make_float4(0.f, 0.f, 0.f, 0.f);
        if (row < n) v = *(const float4*)&X[(size_t)row * 128 + c8];
        *(float4*)&xs[r][c8] = v;
    }
    __syncthreads();
    int c = tid & 15, r = tid >> 4;
    float acc = 0.f;
#pragma unroll 4
    for (int k = 0; k < 128; k += 2) {
        half2_t xv = *(const half2_t*)&xs[r][k];
        acc = fmaf((float)xv[0], wl[k * 16 + c], acc);
        acc = fmaf((float)xv[1], wl[(k + 1) * 16 + c], acc);
    }
    int row = row0 + r;
    if (row < n) out[(size_t)row * 16 + c] = acc + bout[c];
}

extern "C" void kernel_launch(void* const* d_in, const int* in_sizes, int n_in,
                              void* d_out, int out_size, void* d_ws, size_t ws_size,
                              hipStream_t stream)
{
    const float* h   = (const float*)d_in[0];
    const int*   src = (const int*)d_in[1];
    const int*   dst = (const int*)d_in[2];
    const float* W1  = (const float*)d_in[3];
    const float* b1  = (const float*)d_in[4];
    const float* W2  = (const float*)d_in[5];
    const float* b2  = (const float*)d_in[6];
    const float* Wc  = (const float*)d_in[7];
    const float* bc  = (const float*)d_in[8];
    float* out = (float*)d_out;

    const int n = in_sizes[0] / 128;   // 100000
    const int E = in_sizes[1];         // 600000
    const int nb = (n + 255) / 256;    // 391 (<=1024)

    char* ws = (char*)d_ws;
    int*   cnt_out = (int*)ws;                      // n
    int*   cnt_in  = cnt_out + n;                   // n
    float* rs_out  = (float*)(cnt_in + n);          // n
    float* rs_in   = rs_out + n;                    // n
    int*   starts  = (int*)(rs_in + n);             // n
    int*   cursor  = starts + n;                    // n
    int*   bsum    = cursor + n;                    // 1024
    int*   eidx    = bsum + 1024;                   // E
    _Float16* WT1  = (_Float16*)(eidx + E);         // 16384
    _Float16* WT2  = WT1 + 16384;                   // 16384
    size_t off = ((size_t)((char*)(WT2 + 16384) - ws) + 255) & ~(size_t)255;
    _Float16* bufA = (_Float16*)(ws + off);         // n*128 f16
    _Float16* bufB = bufA + (size_t)n * 128;        // n*128 f16

    // degrees + CSR + f16 weight transpose
    hipMemsetAsync(cnt_out, 0, (size_t)2 * n * sizeof(int), stream);
    count_kernel<<<(E + 255) / 256, 256, 0, stream>>>(src, dst, cnt_out, cnt_in, E);
    rs_kernel<<<(2 * n + 255) / 256, 256, 0, stream>>>(cnt_out, rs_out, 2 * n);
    scan1_kernel<<<nb, 256, 0, stream>>>(cnt_in, starts, bsum, n);
    scan2_kernel<<<1, 1024, 0, stream>>>(bsum, nb);
    scan3_kernel<<<nb, 256, 0, stream>>>(starts, cursor, bsum, n);
    fill_kernel<<<(E + 255) / 256, 256, 0, stream>>>(src, dst, cursor, eidx, E);
    wt_kernel<<<128, 256, 0, stream>>>(W1, W2, WT1, WT2);

    int gblocks = (n + 127) / 128;   // MFMA GEMM blocks (128 rows each)
    int ablocks = (n + 3) / 4;       // gather: 4 waves/block, 1 wave/node

    // Layer 1
    gemm_mfma<0><<<gblocks, 256, 0, stream>>>(h, WT1, rs_out, bufA, n);
    gather_f16<0><<<ablocks, 256, 0, stream>>>(bufA, eidx, starts, rs_in, rs_out, b1, bufB, n, E);

    // Layer 2
    gemm_mfma<1><<<gblocks, 256, 0, stream>>>(bufB, WT2, rs_out, bufA, n);
    gather_f16<1><<<ablocks, 256, 0, stream>>>(bufA, eidx, starts, rs_in, rs_out, b2, bufB, n, E);

    // Classifier
    classifier_kernel<<<(n + 15) / 16, 256, 0, stream>>>(bufB, Wc, bc, out, n);
}

// Round 5
// 250.026 us; speedup vs baseline: 21.6035x; 1.2249x over previous
//
#include <hip/hip_runtime.h>

// GCN: 2x GraphConv(128->128, norm='both') + ReLU, then Linear(128->16).
// N=100000, E=600000, D=128, C=16.
//
// Round 5: gemm gets coalesced memory paths (A staged via XOR-swizzled LDS,
// W pre-packed frag-major so B loads coalesce); gather gets a 4-edge unroll
// to break the eidx->row dependent-latency chain (round-4: 900cyc/2 edges).

typedef __attribute__((ext_vector_type(4))) _Float16 half4_t;
typedef __attribute__((ext_vector_type(2))) _Float16 half2_t;
typedef __attribute__((ext_vector_type(16))) float floatx16;

__global__ __launch_bounds__(256) void count_kernel(
    const int* __restrict__ src, const int* __restrict__ dst,
    int* __restrict__ cnt_out, int* __restrict__ cnt_in, int E)
{
    int i = blockIdx.x * blockDim.x + threadIdx.x;
    if (i < E) {
        atomicAdd(&cnt_out[src[i]], 1);
        atomicAdd(&cnt_in[dst[i]], 1);
    }
}

__global__ __launch_bounds__(256) void rs_kernel(
    const int* __restrict__ cnt, float* __restrict__ rs, int m)
{
    int i = blockIdx.x * blockDim.x + threadIdx.x;
    if (i < m) rs[i] = rsqrtf(fmaxf((float)cnt[i], 1.0f));
}

__global__ __launch_bounds__(256) void scan1_kernel(
    const int* __restrict__ cnt, int* __restrict__ excl,
    int* __restrict__ bsum, int n)
{
    __shared__ int tmp[256];
    int i = blockIdx.x * 256 + threadIdx.x;
    int v = (i < n) ? cnt[i] : 0;
    tmp[threadIdx.x] = v;
    __syncthreads();
    for (int off = 1; off < 256; off <<= 1) {
        int t = (threadIdx.x >= off) ? tmp[threadIdx.x - off] : 0;
        __syncthreads();
        tmp[threadIdx.x] += t;
        __syncthreads();
    }
    if (i < n) excl[i] = tmp[threadIdx.x] - v;
    if (threadIdx.x == 255) bsum[blockIdx.x] = tmp[255];
}

__global__ __launch_bounds__(1024) void scan2_kernel(int* __restrict__ bsum, int nb)
{
    __shared__ int tmp[1024];
    int t = threadIdx.x;
    int v = (t < nb) ? bsum[t] : 0;
    tmp[t] = v;
    __syncthreads();
    for (int off = 1; off < 1024; off <<= 1) {
        int x = (t >= off) ? tmp[t - off] : 0;
        __syncthreads();
        tmp[t] += x;
        __syncthreads();
    }
    if (t < nb) bsum[t] = tmp[t] - v;   // exclusive
}

__global__ __launch_bounds__(256) void scan3_kernel(
    int* __restrict__ excl, int* __restrict__ cursor,
    const int* __restrict__ bsum, int n)
{
    int i = blockIdx.x * 256 + threadIdx.x;
    if (i < n) {
        int v = excl[i] + bsum[blockIdx.x];
        excl[i] = v;
        cursor[i] = v;
    }
}

__global__ __launch_bounds__(256) void fill_kernel(
    const int* __restrict__ src, const int* __restrict__ dst,
    int* __restrict__ cursor, int* __restrict__ eidx, int E)
{
    int e = blockIdx.x * blockDim.x + threadIdx.x;
    if (e < E) {
        int p = atomicAdd(&cursor[dst[e]], 1);
        eidx[p] = src[e];
    }
}

// Pack W (fp32 [k][col]) into frag-major f16:
//   WB[ ((kt*2+g)*128 + col)*4 + i ] = W[(kt*8+g*4+i)*128 + col]
// so a wave's B-frag load (lane m, group g, tile nt, step kt) is the half4 at
// WB + ((kt*2+g)*128 + nt*32 + m)*4  -> consecutive lanes = consecutive 8 B.
__global__ __launch_bounds__(256) void wpack_kernel(
    const float* __restrict__ W1, const float* __restrict__ W2,
    _Float16* __restrict__ WB1, _Float16* __restrict__ WB2)
{
    int gid = blockIdx.x * 256 + threadIdx.x;      // 0..32767
    int j = gid & 16383;
    int i   = j & 3;
    int col = (j >> 2) & 127;
    int g   = (j >> 9) & 1;
    int kt  = j >> 10;
    int k = kt * 8 + g * 4 + i;
    if (gid < 16384) WB1[j] = (_Float16)W1[k * 128 + col];
    else             WB2[j] = (_Float16)W2[k * 128 + col];
}

// T[n][128] f16 = prologue(X) @ W via v_mfma_f32_32x32x8f16 (fp32 accum).
// Block = 4 waves, 128 rows. A staged in LDS (f16, XOR-swizzled row-major:
// byte ^= (row&7)<<4 -> frag ds_read_b64 <=4-way instead of 32-way).
// B read from global frag-major WB (coalesced, 32 KB, L2-hot).
// MODE 0: X fp32, A = X*rs_out[row].  MODE 1: X f16, A = X.
template <int MODE>
__global__ __launch_bounds__(256) void gemm_mfma(
    const void* __restrict__ Xv, const _Float16* __restrict__ WB,
    const float* __restrict__ rs_out, _Float16* __restrict__ T, int n)
{
    __shared__ _Float16 xa[128 * 128];   // 32 KB
    char* xab = (char*)xa;

    const int tid  = threadIdx.x;
    const int lane = tid & 63;
    const int wv   = tid >> 6;
    const int m    = lane & 31;
    const int g    = lane >> 5;
    const int rbase = blockIdx.x * 128 + wv * 32;

    // ---- stage A: rows [blk*128, +128), 128 cols, coalesced global reads ----
    {
        const int C = (tid & 31) * 4;          // half4 column
        const int rsub = tid >> 5;             // 8 rows per pass
#pragma unroll
        for (int p = 0; p < 16; ++p) {
            int R = p * 8 + rsub;
            int row = blockIdx.x * 128 + R;
            half4_t a;
            if (row < n) {
                if (MODE == 0) {
                    const float* X = (const float*)Xv;
                    float s = rs_out[row];
                    float4 v = *(const float4*)&X[(size_t)row * 128 + C];
                    a[0] = (_Float16)(v.x * s);
                    a[1] = (_Float16)(v.y * s);
                    a[2] = (_Float16)(v.z * s);
                    a[3] = (_Float16)(v.w * s);
                } else {
                    const _Float16* X = (const _Float16*)Xv;
                    a = *(const half4_t*)&X[(size_t)row * 128 + C];
                }
            } else {
                a[0] = a[1] = a[2] = a[3] = (_Float16)0.f;
            }
            int byte = (R * 256 + C * 2) ^ ((R & 7) << 4);
            *(half4_t*)(xab + byte) = a;
        }
    }
    __syncthreads();

    // ---- MFMA main loop ----
    floatx16 acc0 = {}, acc1 = {}, acc2 = {}, acc3 = {};
    const int arow = wv * 32 + m;
    const int abase = (arow * 256) ^ ((m & 7) << 4);   // row term; col XORs below
    const _Float16* wb = WB + (size_t)(g * 128 + m) * 4;

#pragma unroll 2
    for (int kt = 0; kt < 16; ++kt) {
        int cbyte = kt * 16 + g * 8;
        half4_t a = *(const half4_t*)(xab + ((arow * 256 + cbyte) ^ ((m & 7) << 4)));
        const _Float16* wk = wb + (size_t)kt * 1024;   // (kt*2)*128*4 halves
        half4_t b0 = *(const half4_t*)(wk);
        half4_t b1 = *(const half4_t*)(wk + 128);      // nt=1: +32 cols *4
        half4_t b2 = *(const half4_t*)(wk + 256);
        half4_t b3 = *(const half4_t*)(wk + 384);
        acc0 = __builtin_amdgcn_mfma_f32_32x32x8f16(a, b0, acc0, 0, 0, 0);
        acc1 = __builtin_amdgcn_mfma_f32_32x32x8f16(a, b1, acc1, 0, 0, 0);
        acc2 = __builtin_amdgcn_mfma_f32_32x32x8f16(a, b2, acc2, 0, 0, 0);
        acc3 = __builtin_amdgcn_mfma_f32_32x32x8f16(a, b3, acc3, 0, 0, 0);
    }

#pragma unroll
    for (int rg = 0; rg < 16; ++rg) {
        int rd = (rg & 3) + 8 * (rg >> 2) + 4 * g;
        int orow = rbase + rd;
        if (orow < n) {
            _Float16* tp = T + (size_t)orow * 128 + m;
            tp[0]  = (_Float16)acc0[rg];
            tp[32] = (_Float16)acc1[rg];
            tp[64] = (_Float16)acc2[rg];
            tp[96] = (_Float16)acc3[rg];
        }
    }
}

// Xout[d][:] = epilogue( sum_{in-edges} T[src][:] ), one wave per node.
// 4-edge unroll: one dwordx4 eidx fetch feeds 4 independent 256 B row loads,
// amortizing the eidx->row dependent-latency chain.
// MODE 0: epi = f16(relu(acc*rs_in+b)*rs_out)  MODE 1: epi = f16(relu(acc*rs_in+b))
template <int MODE>
__global__ __launch_bounds__(256) void gather_f16(
    const _Float16* __restrict__ T, const int* __restrict__ eidx,
    const int* __restrict__ starts, const float* __restrict__ rs_in,
    const float* __restrict__ rs_out, const float* __restrict__ bias,
    _Float16* __restrict__ Xout, int n, int E)
{
    int wid = (blockIdx.x * 256 + threadIdx.x) >> 6;
    int lane = threadIdx.x & 63;
    if (wid >= n) return;
    int s0 = starts[wid];
    int s1 = (wid + 1 < n) ? starts[wid + 1] : E;
    float a0 = 0.f, a1 = 0.f, b0 = 0.f, b1 = 0.f;
    float c0 = 0.f, c1 = 0.f, d0 = 0.f, d1 = 0.f;
    int j = s0;
    for (; j + 3 < s1; j += 4) {
        int4 s4 = *(const int4*)&eidx[j];
        half2_t va = *(const half2_t*)&T[(size_t)s4.x * 128 + lane * 2];
        half2_t vb = *(const half2_t*)&T[(size_t)s4.y * 128 + lane * 2];
        half2_t vc = *(const half2_t*)&T[(size_t)s4.z * 128 + lane * 2];
        half2_t vd = *(const half2_t*)&T[(size_t)s4.w * 128 + lane * 2];
        a0 += (float)va[0]; a1 += (float)va[1];
        b0 += (float)vb[0]; b1 += (float)vb[1];
        c0 += (float)vc[0]; c1 += (float)vc[1];
        d0 += (float)vd[0]; d1 += (float)vd[1];
    }
    if (j + 1 < s1) {
        int sA = eidx[j], sB = eidx[j + 1];
        half2_t va = *(const half2_t*)&T[(size_t)sA * 128 + lane * 2];
        half2_t vb = *(const half2_t*)&T[(size_t)sB * 128 + lane * 2];
        a0 += (float)va[0]; a1 += (float)va[1];
        b0 += (float)vb[0]; b1 += (float)vb[1];
        j += 2;
    }
    if (j < s1) {
        int sA = eidx[j];
        half2_t va = *(const half2_t*)&T[(size_t)sA * 128 + lane * 2];
        c0 += (float)va[0]; c1 += (float)va[1];
    }
    float t0 = (a0 + b0) + (c0 + d0);
    float t1 = (a1 + b1) + (c1 + d1);
    float ri = rs_in[wid];
    float x0 = fmaxf(fmaf(t0, ri, bias[lane * 2 + 0]), 0.f);
    float x1 = fmaxf(fmaf(t1, ri, bias[lane * 2 + 1]), 0.f);
    if (MODE == 0) {
        float ro = rs_out[wid];
        x0 *= ro; x1 *= ro;
    }
    half2_t o;
    o[0] = (_Float16)x0;
    o[1] = (_Float16)x1;
    *(half2_t*)&Xout[(size_t)wid * 128 + lane * 2] = o;
}

// out[n,16] = X3 @ Wc + bc   (X3 f16 already has relu/bias applied)
__global__ __launch_bounds__(256) void classifier_kernel(
    const _Float16* __restrict__ X, const float* __restrict__ Wc,
    const float* __restrict__ bout, float* __restrict__ out, int n)
{
    __shared__ float wl[128 * 16];       // 8 KB
    __shared__ _Float16 xs[16][128];     // 4 KB
    const int tid = threadIdx.x;
    const int row0 = blockIdx.x * 16;
#pragma unroll
    for (int i0 = 0; i0 < 2; ++i0) {
        int i = tid + i0 * 256;
        ((float4*)wl)[i] = ((const float4*)Wc)[i];
    }
    {
        int r = tid >> 4, c8 = (tid & 15) * 8;
        int row = row0 + r;
        float4 v = make_float4(0.f, 0.f, 0.f, 0.f);
        if (row < n) v = *(const float4*)&X[(size_t)row * 128 + c8];
        *(float4*)&xs[r][c8] = v;
    }
    __syncthreads();
    int c = tid & 15, r = tid >> 4;
    float acc = 0.f;
#pragma unroll 4
    for (int k = 0; k < 128; k += 2) {
        half2_t xv = *(const half2_t*)&xs[r][k];
        acc = fmaf((float)xv[0], wl[k * 16 + c], acc);
        acc = fmaf((float)xv[1], wl[(k + 1) * 16 + c], acc);
    }
    int row = row0 + r;
    if (row < n) out[(size_t)row * 16 + c] = acc + bout[c];
}

extern "C" void kernel_launch(void* const* d_in, const int* in_sizes, int n_in,
                              void* d_out, int out_size, void* d_ws, size_t ws_size,
                              hipStream_t stream)
{
    const float* h   = (const float*)d_in[0];
    const int*   src = (const int*)d_in[1];
    const int*   dst = (const int*)d_in[2];
    const float* W1  = (const float*)d_in[3];
    const float* b1  = (const float*)d_in[4];
    const float* W2  = (const float*)d_in[5];
    const float* b2  = (const float*)d_in[6];
    const float* Wc  = (const float*)d_in[7];
    const float* bc  = (const float*)d_in[8];
    float* out = (float*)d_out;

    const int n = in_sizes[0] / 128;   // 100000
    const int E = in_sizes[1];         // 600000
    const int nb = (n + 255) / 256;    // 391 (<=1024)

    char* ws = (char*)d_ws;
    int*   cnt_out = (int*)ws;                      // n
    int*   cnt_in  = cnt_out + n;                   // n
    float* rs_out  = (float*)(cnt_in + n);          // n
    float* rs_in   = rs_out + n;                    // n
    int*   starts  = (int*)(rs_in + n);             // n
    int*   cursor  = starts + n;                    // n
    int*   bsum    = cursor + n;                    // 1024
    int*   eidx    = bsum + 1024;                   // E
    _Float16* WB1  = (_Float16*)(eidx + E);         // 16384
    _Float16* WB2  = WB1 + 16384;                   // 16384
    size_t off = ((size_t)((char*)(WB2 + 16384) - ws) + 255) & ~(size_t)255;
    _Float16* bufA = (_Float16*)(ws + off);         // n*128 f16
    _Float16* bufB = bufA + (size_t)n * 128;        // n*128 f16

    hipMemsetAsync(cnt_out, 0, (size_t)2 * n * sizeof(int), stream);
    count_kernel<<<(E + 255) / 256, 256, 0, stream>>>(src, dst, cnt_out, cnt_in, E);
    rs_kernel<<<(2 * n + 255) / 256, 256, 0, stream>>>(cnt_out, rs_out, 2 * n);
    scan1_kernel<<<nb, 256, 0, stream>>>(cnt_in, starts, bsum, n);
    scan2_kernel<<<1, 1024, 0, stream>>>(bsum, nb);
    scan3_kernel<<<nb, 256, 0, stream>>>(starts, cursor, bsum, n);
    fill_kernel<<<(E + 255) / 256, 256, 0, stream>>>(src, dst, cursor, eidx, E);
    wpack_kernel<<<128, 256, 0, stream>>>(W1, W2, WB1, WB2);

    int gblocks = (n + 127) / 128;   // 782
    int ablocks = (n + 3) / 4;       // gather: 4 waves/block, 1 wave/node

    // Layer 1
    gemm_mfma<0><<<gblocks, 256, 0, stream>>>(h, WB1, rs_out, bufA, n);
    gather_f16<0><<<ablocks, 256, 0, stream>>>(bufA, eidx, starts, rs_in, rs_out, b1, bufB, n, E);

    // Layer 2
    gemm_mfma<1><<<gblocks, 256, 0, stream>>>(bufB, WB2, rs_out, bufA, n);
    gather_f16<1><<<ablocks, 256, 0, stream>>>(bufA, eidx, starts, rs_in, rs_out, b2, bufB, n, E);

    // Classifier
    classifier_kernel<<<(n + 15) / 16, 256, 0, stream>>>(bufB, Wc, bc, out, n);
}

// Round 6
// 239.184 us; speedup vs baseline: 22.5827x; 1.0453x over previous
//
#include <hip/hip_runtime.h>

// GCN: 2x GraphConv(128->128, norm='both') + ReLU, then Linear(128->16).
// N=100000, E=600000, D=128, C=16.
//
// Round 6: CSR-build overhaul.
//  - Degree counters spread to 1 per 64B line (cnt[16*i]) -> no same-line
//    atomic serialization (round-5: 96 increments/line, count=48.5us).
//  - count_kernel captures per-edge rank from the atomicAdd return value;
//    fill_kernel becomes atomic-free: eidx[starts[dst]+rank] = src.
//  - count processes 4 edges/thread (int4 loads).

typedef __attribute__((ext_vector_type(4))) _Float16 half4_t;
typedef __attribute__((ext_vector_type(2))) _Float16 half2_t;
typedef __attribute__((ext_vector_type(16))) float floatx16;

#define SPREAD 16   // ints per counter slot (64 B line each)

// 4 edges/thread; counters spread; rank captured from cnt_in atomic return.
__global__ __launch_bounds__(256) void count_kernel(
    const int* __restrict__ src, const int* __restrict__ dst,
    int* __restrict__ cntO, int* __restrict__ cntI,
    int* __restrict__ rank, int E)
{
    int t = blockIdx.x * blockDim.x + threadIdx.x;
    int e0 = t * 4;
    if (e0 + 3 < E) {
        int4 s = *(const int4*)&src[e0];
        int4 d = *(const int4*)&dst[e0];
        atomicAdd(&cntO[s.x * SPREAD], 1);
        atomicAdd(&cntO[s.y * SPREAD], 1);
        atomicAdd(&cntO[s.z * SPREAD], 1);
        atomicAdd(&cntO[s.w * SPREAD], 1);
        int4 r;
        r.x = atomicAdd(&cntI[d.x * SPREAD], 1);
        r.y = atomicAdd(&cntI[d.y * SPREAD], 1);
        r.z = atomicAdd(&cntI[d.z * SPREAD], 1);
        r.w = atomicAdd(&cntI[d.w * SPREAD], 1);
        *(int4*)&rank[e0] = r;
    } else {
        for (int e = e0; e < E; ++e) {
            atomicAdd(&cntO[src[e] * SPREAD], 1);
            rank[e] = atomicAdd(&cntI[dst[e] * SPREAD], 1);
        }
    }
}

// rs_out[i]=rsqrt(max(degO,1)); rs_in[i]=rsqrt(max(degI,1))  (spread reads)
__global__ __launch_bounds__(256) void rs_kernel(
    const int* __restrict__ cntO, const int* __restrict__ cntI,
    float* __restrict__ rs_out, float* __restrict__ rs_in, int n)
{
    int i = blockIdx.x * blockDim.x + threadIdx.x;
    if (i < n) {
        rs_out[i] = rsqrtf(fmaxf((float)cntO[i * SPREAD], 1.0f));
        rs_in[i]  = rsqrtf(fmaxf((float)cntI[i * SPREAD], 1.0f));
    }
}

// exclusive scan of spread cnt_in -> compact starts
__global__ __launch_bounds__(256) void scan1_kernel(
    const int* __restrict__ cntI, int* __restrict__ excl,
    int* __restrict__ bsum, int n)
{
    __shared__ int tmp[256];
    int i = blockIdx.x * 256 + threadIdx.x;
    int v = (i < n) ? cntI[i * SPREAD] : 0;
    tmp[threadIdx.x] = v;
    __syncthreads();
    for (int off = 1; off < 256; off <<= 1) {
        int t = (threadIdx.x >= off) ? tmp[threadIdx.x - off] : 0;
        __syncthreads();
        tmp[threadIdx.x] += t;
        __syncthreads();
    }
    if (i < n) excl[i] = tmp[threadIdx.x] - v;
    if (threadIdx.x == 255) bsum[blockIdx.x] = tmp[255];
}

__global__ __launch_bounds__(1024) void scan2_kernel(int* __restrict__ bsum, int nb)
{
    __shared__ int tmp[1024];
    int t = threadIdx.x;
    int v = (t < nb) ? bsum[t] : 0;
    tmp[t] = v;
    __syncthreads();
    for (int off = 1; off < 1024; off <<= 1) {
        int x = (t >= off) ? tmp[t - off] : 0;
        __syncthreads();
        tmp[t] += x;
        __syncthreads();
    }
    if (t < nb) bsum[t] = tmp[t] - v;   // exclusive
}

__global__ __launch_bounds__(256) void scan3_kernel(
    int* __restrict__ excl, const int* __restrict__ bsum, int n)
{
    int i = blockIdx.x * 256 + threadIdx.x;
    if (i < n) excl[i] += bsum[blockIdx.x];
}

// atomic-free fill: slot precomputed from starts + per-edge rank
__global__ __launch_bounds__(256) void fill_kernel(
    const int* __restrict__ src, const int* __restrict__ dst,
    const int* __restrict__ rank, const int* __restrict__ starts,
    int* __restrict__ eidx, int E)
{
    int e = blockIdx.x * blockDim.x + threadIdx.x;
    if (e < E) {
        eidx[starts[dst[e]] + rank[e]] = src[e];
    }
}

// Pack W (fp32 [k][col]) into frag-major f16:
//   WB[ ((kt*2+g)*128 + col)*4 + i ] = W[(kt*8+g*4+i)*128 + col]
__global__ __launch_bounds__(256) void wpack_kernel(
    const float* __restrict__ W1, const float* __restrict__ W2,
    _Float16* __restrict__ WB1, _Float16* __restrict__ WB2)
{
    int gid = blockIdx.x * 256 + threadIdx.x;      // 0..32767
    int j = gid & 16383;
    int i   = j & 3;
    int col = (j >> 2) & 127;
    int g   = (j >> 9) & 1;
    int kt  = j >> 10;
    int k = kt * 8 + g * 4 + i;
    if (gid < 16384) WB1[j] = (_Float16)W1[k * 128 + col];
    else             WB2[j] = (_Float16)W2[k * 128 + col];
}

// T[n][128] f16 = prologue(X) @ W via v_mfma_f32_32x32x8f16 (fp32 accum).
// Block = 4 waves, 128 rows. A staged in XOR-swizzled LDS; B from frag-major
// WB in global (coalesced, 32 KB, L2-hot).
// MODE 0: X fp32, A = X*rs_out[row].  MODE 1: X f16, A = X.
template <int MODE>
__global__ __launch_bounds__(256) void gemm_mfma(
    const void* __restrict__ Xv, const _Float16* __restrict__ WB,
    const float* __restrict__ rs_out, _Float16* __restrict__ T, int n)
{
    __shared__ _Float16 xa[128 * 128];   // 32 KB
    char* xab = (char*)xa;

    const int tid  = threadIdx.x;
    const int lane = tid & 63;
    const int wv   = tid >> 6;
    const int m    = lane & 31;
    const int g    = lane >> 5;
    const int rbase = blockIdx.x * 128 + wv * 32;

    // ---- stage A: rows [blk*128, +128), coalesced global reads ----
    {
        const int C = (tid & 31) * 4;          // half4 column
        const int rsub = tid >> 5;             // 8 rows per pass
#pragma unroll
        for (int p = 0; p < 16; ++p) {
            int R = p * 8 + rsub;
            int row = blockIdx.x * 128 + R;
            half4_t a;
            if (row < n) {
                if (MODE == 0) {
                    const float* X = (const float*)Xv;
                    float s = rs_out[row];
                    float4 v = *(const float4*)&X[(size_t)row * 128 + C];
                    a[0] = (_Float16)(v.x * s);
                    a[1] = (_Float16)(v.y * s);
                    a[2] = (_Float16)(v.z * s);
                    a[3] = (_Float16)(v.w * s);
                } else {
                    const _Float16* X = (const _Float16*)Xv;
                    a = *(const half4_t*)&X[(size_t)row * 128 + C];
                }
            } else {
                a[0] = a[1] = a[2] = a[3] = (_Float16)0.f;
            }
            int byte = (R * 256 + C * 2) ^ ((R & 7) << 4);
            *(half4_t*)(xab + byte) = a;
        }
    }
    __syncthreads();

    // ---- MFMA main loop ----
    floatx16 acc0 = {}, acc1 = {}, acc2 = {}, acc3 = {};
    const int arow = wv * 32 + m;
    const _Float16* wb = WB + (size_t)(g * 128 + m) * 4;

#pragma unroll 2
    for (int kt = 0; kt < 16; ++kt) {
        int cbyte = kt * 16 + g * 8;
        half4_t a = *(const half4_t*)(xab + ((arow * 256 + cbyte) ^ ((m & 7) << 4)));
        const _Float16* wk = wb + (size_t)kt * 1024;
        half4_t b0 = *(const half4_t*)(wk);
        half4_t b1 = *(const half4_t*)(wk + 128);
        half4_t b2 = *(const half4_t*)(wk + 256);
        half4_t b3 = *(const half4_t*)(wk + 384);
        acc0 = __builtin_amdgcn_mfma_f32_32x32x8f16(a, b0, acc0, 0, 0, 0);
        acc1 = __builtin_amdgcn_mfma_f32_32x32x8f16(a, b1, acc1, 0, 0, 0);
        acc2 = __builtin_amdgcn_mfma_f32_32x32x8f16(a, b2, acc2, 0, 0, 0);
        acc3 = __builtin_amdgcn_mfma_f32_32x32x8f16(a, b3, acc3, 0, 0, 0);
    }

#pragma unroll
    for (int rg = 0; rg < 16; ++rg) {
        int rd = (rg & 3) + 8 * (rg >> 2) + 4 * g;
        int orow = rbase + rd;
        if (orow < n) {
            _Float16* tp = T + (size_t)orow * 128 + m;
            tp[0]  = (_Float16)acc0[rg];
            tp[32] = (_Float16)acc1[rg];
            tp[64] = (_Float16)acc2[rg];
            tp[96] = (_Float16)acc3[rg];
        }
    }
}

// Xout[d][:] = epilogue( sum_{in-edges} T[src][:] ), one wave per node.
// 4-edge unroll: one dwordx4 eidx fetch feeds 4 independent 256 B row loads.
// MODE 0: epi = f16(relu(acc*rs_in+b)*rs_out)  MODE 1: epi = f16(relu(acc*rs_in+b))
template <int MODE>
__global__ __launch_bounds__(256) void gather_f16(
    const _Float16* __restrict__ T, const int* __restrict__ eidx,
    const int* __restrict__ starts, const float* __restrict__ rs_in,
    const float* __restrict__ rs_out, const float* __restrict__ bias,
    _Float16* __restrict__ Xout, int n, int E)
{
    int wid = (blockIdx.x * 256 + threadIdx.x) >> 6;
    int lane = threadIdx.x & 63;
    if (wid >= n) return;
    int s0 = starts[wid];
    int s1 = (wid + 1 < n) ? starts[wid + 1] : E;
    float a0 = 0.f, a1 = 0.f, b0 = 0.f, b1 = 0.f;
    float c0 = 0.f, c1 = 0.f, d0 = 0.f, d1 = 0.f;
    int j = s0;
    for (; j + 3 < s1; j += 4) {
        int4 s4 = *(const int4*)&eidx[j];
        half2_t va = *(const half2_t*)&T[(size_t)s4.x * 128 + lane * 2];
        half2_t vb = *(const half2_t*)&T[(size_t)s4.y * 128 + lane * 2];
        half2_t vc = *(const half2_t*)&T[(size_t)s4.z * 128 + lane * 2];
        half2_t vd = *(const half2_t*)&T[(size_t)s4.w * 128 + lane * 2];
        a0 += (float)va[0]; a1 += (float)va[1];
        b0 += (float)vb[0]; b1 += (float)vb[1];
        c0 += (float)vc[0]; c1 += (float)vc[1];
        d0 += (float)vd[0]; d1 += (float)vd[1];
    }
    if (j + 1 < s1) {
        int sA = eidx[j], sB = eidx[j + 1];
        half2_t va = *(const half2_t*)&T[(size_t)sA * 128 + lane * 2];
        half2_t vb = *(const half2_t*)&T[(size_t)sB * 128 + lane * 2];
        a0 += (float)va[0]; a1 += (float)va[1];
        b0 += (float)vb[0]; b1 += (float)vb[1];
        j += 2;
    }
    if (j < s1) {
        int sA = eidx[j];
        half2_t va = *(const half2_t*)&T[(size_t)sA * 128 + lane * 2];
        c0 += (float)va[0]; c1 += (float)va[1];
    }
    float t0 = (a0 + b0) + (c0 + d0);
    float t1 = (a1 + b1) + (c1 + d1);
    float ri = rs_in[wid];
    float x0 = fmaxf(fmaf(t0, ri, bias[lane * 2 + 0]), 0.f);
    float x1 = fmaxf(fmaf(t1, ri, bias[lane * 2 + 1]), 0.f);
    if (MODE == 0) {
        float ro = rs_out[wid];
        x0 *= ro; x1 *= ro;
    }
    half2_t o;
    o[0] = (_Float16)x0;
    o[1] = (_Float16)x1;
    *(half2_t*)&Xout[(size_t)wid * 128 + lane * 2] = o;
}

// out[n,16] = X3 @ Wc + bc   (X3 f16 already has relu/bias applied)
__global__ __launch_bounds__(256) void classifier_kernel(
    const _Float16* __restrict__ X, const float* __restrict__ Wc,
    const float* __restrict__ bout, float* __restrict__ out, int n)
{
    __shared__ float wl[128 * 16];       // 8 KB
    __shared__ _Float16 xs[16][128];     // 4 KB
    const int tid = threadIdx.x;
    const int row0 = blockIdx.x * 16;
#pragma unroll
    for (int i0 = 0; i0 < 2; ++i0) {
        int i = tid + i0 * 256;
        ((float4*)wl)[i] = ((const float4*)Wc)[i];
    }
    {
        int r = tid >> 4, c8 = (tid & 15) * 8;
        int row = row0 + r;
        float4 v = make_float4(0.f, 0.f, 0.f, 0.f);
        if (row < n) v = *(const float4*)&X[(size_t)row * 128 + c8];
        *(float4*)&xs[r][c8] = v;
    }
    __syncthreads();
    int c = tid & 15, r = tid >> 4;
    float acc = 0.f;
#pragma unroll 4
    for (int k = 0; k < 128; k += 2) {
        half2_t xv = *(const half2_t*)&xs[r][k];
        acc = fmaf((float)xv[0], wl[k * 16 + c], acc);
        acc = fmaf((float)xv[1], wl[(k + 1) * 16 + c], acc);
    }
    int row = row0 + r;
    if (row < n) out[(size_t)row * 16 + c] = acc + bout[c];
}

extern "C" void kernel_launch(void* const* d_in, const int* in_sizes, int n_in,
                              void* d_out, int out_size, void* d_ws, size_t ws_size,
                              hipStream_t stream)
{
    const float* h   = (const float*)d_in[0];
    const int*   src = (const int*)d_in[1];
    const int*   dst = (const int*)d_in[2];
    const float* W1  = (const float*)d_in[3];
    const float* b1  = (const float*)d_in[4];
    const float* W2  = (const float*)d_in[5];
    const float* b2  = (const float*)d_in[6];
    const float* Wc  = (const float*)d_in[7];
    const float* bc  = (const float*)d_in[8];
    float* out = (float*)d_out;

    const int n = in_sizes[0] / 128;   // 100000
    const int E = in_sizes[1];         // 600000
    const int nb = (n + 255) / 256;    // 391 (<=1024)

    char* ws = (char*)d_ws;
    int*   cntO    = (int*)ws;                       // n*SPREAD ints (6.4 MB)
    int*   cntI    = cntO + (size_t)n * SPREAD;      // n*SPREAD ints
    int*   rank    = cntI + (size_t)n * SPREAD;      // E
    float* rs_out  = (float*)(rank + E);             // n
    float* rs_in   = rs_out + n;                     // n
    int*   starts  = (int*)(rs_in + n);              // n
    int*   bsum    = starts + n;                     // 1024
    int*   eidx    = bsum + 1024;                    // E
    _Float16* WB1  = (_Float16*)(eidx + E);          // 16384
    _Float16* WB2  = WB1 + 16384;                    // 16384
    size_t off = ((size_t)((char*)(WB2 + 16384) - ws) + 255) & ~(size_t)255;
    _Float16* bufA = (_Float16*)(ws + off);          // n*128 f16
    _Float16* bufB = bufA + (size_t)n * 128;         // n*128 f16

    hipMemsetAsync(cntO, 0, (size_t)2 * n * SPREAD * sizeof(int), stream);
    count_kernel<<<(E / 4 + 255) / 256, 256, 0, stream>>>(src, dst, cntO, cntI, rank, E);
    rs_kernel<<<(n + 255) / 256, 256, 0, stream>>>(cntO, cntI, rs_out, rs_in, n);
    scan1_kernel<<<nb, 256, 0, stream>>>(cntI, starts, bsum, n);
    scan2_kernel<<<1, 1024, 0, stream>>>(bsum, nb);
    scan3_kernel<<<nb, 256, 0, stream>>>(starts, bsum, n);
    fill_kernel<<<(E + 255) / 256, 256, 0, stream>>>(src, dst, rank, starts, eidx, E);
    wpack_kernel<<<128, 256, 0, stream>>>(W1, W2, WB1, WB2);

    int gblocks = (n + 127) / 128;   // 782
    int ablocks = (n + 3) / 4;       // gather: 4 waves/block, 1 wave/node

    // Layer 1
    gemm_mfma<0><<<gblocks, 256, 0, stream>>>(h, WB1, rs_out, bufA, n);
    gather_f16<0><<<ablocks, 256, 0, stream>>>(bufA, eidx, starts, rs_in, rs_out, b1, bufB, n, E);

    // Layer 2
    gemm_mfma<1><<<gblocks, 256, 0, stream>>>(bufB, WB2, rs_out, bufA, n);
    gather_f16<1><<<ablocks, 256, 0, stream>>>(bufA, eidx, starts, rs_in, rs_out, b2, bufB, n, E);

    // Classifier
    classifier_kernel<<<(n + 15) / 16, 256, 0, stream>>>(bufB, Wc, bc, out, n);
}

// Round 7
// 210.346 us; speedup vs baseline: 25.6787x; 1.1371x over previous
//
#include <hip/hip_runtime.h>

// GCN: 2x GraphConv(128->128, norm='both') + ReLU, then Linear(128->16).
// N=100000, E=600000, D=128, C=16.
//
// Round 7:
//  - count: REVERT spread counters (r6 regression 48->67us: scattered atomics
//    are service/latency bound; want compact cache-hot bins + max waves, not
//    line spreading). Keep rank capture + atomic-free fill (r6 keeper).
//  - gather: 4 nodes/wave (16-lane group per node, half8/lane) -> 4x the
//    independent row loads in flight per wave (latency-chain amortization).

typedef __attribute__((ext_vector_type(4))) _Float16 half4_t;
typedef __attribute__((ext_vector_type(8))) _Float16 half8_t;
typedef __attribute__((ext_vector_type(16))) float floatx16;

// 1 edge/thread, compact counters; rank = within-node arrival order (free).
__global__ __launch_bounds__(256) void count_kernel(
    const int* __restrict__ src, const int* __restrict__ dst,
    int* __restrict__ cntO, int* __restrict__ cntI,
    int* __restrict__ rank, int E)
{
    int e = blockIdx.x * blockDim.x + threadIdx.x;
    if (e < E) {
        atomicAdd(&cntO[src[e]], 1);
        rank[e] = atomicAdd(&cntI[dst[e]], 1);
    }
}

__global__ __launch_bounds__(256) void rs_kernel(
    const int* __restrict__ cntO, const int* __restrict__ cntI,
    float* __restrict__ rs_out, float* __restrict__ rs_in, int n)
{
    int i = blockIdx.x * blockDim.x + threadIdx.x;
    if (i < n) {
        rs_out[i] = rsqrtf(fmaxf((float)cntO[i], 1.0f));
        rs_in[i]  = rsqrtf(fmaxf((float)cntI[i], 1.0f));
    }
}

__global__ __launch_bounds__(256) void scan1_kernel(
    const int* __restrict__ cntI, int* __restrict__ excl,
    int* __restrict__ bsum, int n)
{
    __shared__ int tmp[256];
    int i = blockIdx.x * 256 + threadIdx.x;
    int v = (i < n) ? cntI[i] : 0;
    tmp[threadIdx.x] = v;
    __syncthreads();
    for (int off = 1; off < 256; off <<= 1) {
        int t = (threadIdx.x >= off) ? tmp[threadIdx.x - off] : 0;
        __syncthreads();
        tmp[threadIdx.x] += t;
        __syncthreads();
    }
    if (i < n) excl[i] = tmp[threadIdx.x] - v;
    if (threadIdx.x == 255) bsum[blockIdx.x] = tmp[255];
}

__global__ __launch_bounds__(1024) void scan2_kernel(int* __restrict__ bsum, int nb)
{
    __shared__ int tmp[1024];
    int t = threadIdx.x;
    int v = (t < nb) ? bsum[t] : 0;
    tmp[t] = v;
    __syncthreads();
    for (int off = 1; off < 1024; off <<= 1) {
        int x = (t >= off) ? tmp[t - off] : 0;
        __syncthreads();
        tmp[t] += x;
        __syncthreads();
    }
    if (t < nb) bsum[t] = tmp[t] - v;   // exclusive
}

__global__ __launch_bounds__(256) void scan3_kernel(
    int* __restrict__ excl, const int* __restrict__ bsum, int n)
{
    int i = blockIdx.x * 256 + threadIdx.x;
    if (i < n) excl[i] += bsum[blockIdx.x];
}

// atomic-free fill: slot precomputed from starts + per-edge rank
__global__ __launch_bounds__(256) void fill_kernel(
    const int* __restrict__ src, const int* __restrict__ dst,
    const int* __restrict__ rank, const int* __restrict__ starts,
    int* __restrict__ eidx, int E)
{
    int e = blockIdx.x * blockDim.x + threadIdx.x;
    if (e < E) {
        eidx[starts[dst[e]] + rank[e]] = src[e];
    }
}

// Pack W (fp32 [k][col]) into frag-major f16:
//   WB[ ((kt*2+g)*128 + col)*4 + i ] = W[(kt*8+g*4+i)*128 + col]
__global__ __launch_bounds__(256) void wpack_kernel(
    const float* __restrict__ W1, const float* __restrict__ W2,
    _Float16* __restrict__ WB1, _Float16* __restrict__ WB2)
{
    int gid = blockIdx.x * 256 + threadIdx.x;      // 0..32767
    int j = gid & 16383;
    int i   = j & 3;
    int col = (j >> 2) & 127;
    int g   = (j >> 9) & 1;
    int kt  = j >> 10;
    int k = kt * 8 + g * 4 + i;
    if (gid < 16384) WB1[j] = (_Float16)W1[k * 128 + col];
    else             WB2[j] = (_Float16)W2[k * 128 + col];
}

// T[n][128] f16 = prologue(X) @ W via v_mfma_f32_32x32x8f16 (fp32 accum).
// Block = 4 waves, 128 rows. A staged in XOR-swizzled LDS; B from frag-major
// WB in global (coalesced, 32 KB, L2-hot).
// MODE 0: X fp32, A = X*rs_out[row].  MODE 1: X f16, A = X.
template <int MODE>
__global__ __launch_bounds__(256) void gemm_mfma(
    const void* __restrict__ Xv, const _Float16* __restrict__ WB,
    const float* __restrict__ rs_out, _Float16* __restrict__ T, int n)
{
    __shared__ _Float16 xa[128 * 128];   // 32 KB
    char* xab = (char*)xa;

    const int tid  = threadIdx.x;
    const int lane = tid & 63;
    const int wv   = tid >> 6;
    const int m    = lane & 31;
    const int g    = lane >> 5;
    const int rbase = blockIdx.x * 128 + wv * 32;

    // ---- stage A: rows [blk*128, +128), coalesced global reads ----
    {
        const int C = (tid & 31) * 4;          // half4 column
        const int rsub = tid >> 5;             // 8 rows per pass
#pragma unroll
        for (int p = 0; p < 16; ++p) {
            int R = p * 8 + rsub;
            int row = blockIdx.x * 128 + R;
            half4_t a;
            if (row < n) {
                if (MODE == 0) {
                    const float* X = (const float*)Xv;
                    float s = rs_out[row];
                    float4 v = *(const float4*)&X[(size_t)row * 128 + C];
                    a[0] = (_Float16)(v.x * s);
                    a[1] = (_Float16)(v.y * s);
                    a[2] = (_Float16)(v.z * s);
                    a[3] = (_Float16)(v.w * s);
                } else {
                    const _Float16* X = (const _Float16*)Xv;
                    a = *(const half4_t*)&X[(size_t)row * 128 + C];
                }
            } else {
                a[0] = a[1] = a[2] = a[3] = (_Float16)0.f;
            }
            int byte = (R * 256 + C * 2) ^ ((R & 7) << 4);
            *(half4_t*)(xab + byte) = a;
        }
    }
    __syncthreads();

    // ---- MFMA main loop ----
    floatx16 acc0 = {}, acc1 = {}, acc2 = {}, acc3 = {};
    const int arow = wv * 32 + m;
    const _Float16* wb = WB + (size_t)(g * 128 + m) * 4;

#pragma unroll 2
    for (int kt = 0; kt < 16; ++kt) {
        int cbyte = kt * 16 + g * 8;
        half4_t a = *(const half4_t*)(xab + ((arow * 256 + cbyte) ^ ((m & 7) << 4)));
        const _Float16* wk = wb + (size_t)kt * 1024;
        half4_t b0 = *(const half4_t*)(wk);
        half4_t b1 = *(const half4_t*)(wk + 128);
        half4_t b2 = *(const half4_t*)(wk + 256);
        half4_t b3 = *(const half4_t*)(wk + 384);
        acc0 = __builtin_amdgcn_mfma_f32_32x32x8f16(a, b0, acc0, 0, 0, 0);
        acc1 = __builtin_amdgcn_mfma_f32_32x32x8f16(a, b1, acc1, 0, 0, 0);
        acc2 = __builtin_amdgcn_mfma_f32_32x32x8f16(a, b2, acc2, 0, 0, 0);
        acc3 = __builtin_amdgcn_mfma_f32_32x32x8f16(a, b3, acc3, 0, 0, 0);
    }

#pragma unroll
    for (int rg = 0; rg < 16; ++rg) {
        int rd = (rg & 3) + 8 * (rg >> 2) + 4 * g;
        int orow = rbase + rd;
        if (orow < n) {
            _Float16* tp = T + (size_t)orow * 128 + m;
            tp[0]  = (_Float16)acc0[rg];
            tp[32] = (_Float16)acc1[rg];
            tp[64] = (_Float16)acc2[rg];
            tp[96] = (_Float16)acc3[rg];
        }
    }
}

// Xout[d][:] = epilogue( sum_{in-edges} T[src][:] ).
// 4 nodes per wave: 16-lane group q handles node wave*4+q; lane holds 16 B
// (half8) of the 256 B row, so a group's row read is one coalesced 256 B
// transaction. 4-edge unroll -> up to 16 independent row loads in flight
// per wave. MODE 0: epi=f16(relu(acc*rs_in+b)*rs_out)  MODE 1: no *rs_out.
template <int MODE>
__global__ __launch_bounds__(256) void gather_f16(
    const _Float16* __restrict__ T, const int* __restrict__ eidx,
    const int* __restrict__ starts, const float* __restrict__ rs_in,
    const float* __restrict__ rs_out, const float* __restrict__ bias,
    _Float16* __restrict__ Xout, int n, int E)
{
    int wave = (blockIdx.x * 256 + threadIdx.x) >> 6;
    int lane = threadIdx.x & 63;
    int q = lane >> 4;            // node group within wave
    int t = lane & 15;            // sublane: halves [t*8, t*8+8)
    int node = wave * 4 + q;
    if (node >= n) return;
    int s0 = starts[node];
    int s1 = (node + 1 < n) ? starts[node + 1] : E;

    float acc[8] = {0.f, 0.f, 0.f, 0.f, 0.f, 0.f, 0.f, 0.f};
    int j = s0;
    for (; j + 3 < s1; j += 4) {
        int4 s4 = *(const int4*)&eidx[j];
        half8_t va = *(const half8_t*)&T[(size_t)s4.x * 128 + t * 8];
        half8_t vb = *(const half8_t*)&T[(size_t)s4.y * 128 + t * 8];
        half8_t vc = *(const half8_t*)&T[(size_t)s4.z * 128 + t * 8];
        half8_t vd = *(const half8_t*)&T[(size_t)s4.w * 128 + t * 8];
#pragma unroll
        for (int i = 0; i < 8; ++i)
            acc[i] += ((float)va[i] + (float)vb[i]) + ((float)vc[i] + (float)vd[i]);
    }
    if (j + 1 < s1) {
        int sA = eidx[j], sB = eidx[j + 1];
        half8_t va = *(const half8_t*)&T[(size_t)sA * 128 + t * 8];
        half8_t vb = *(const half8_t*)&T[(size_t)sB * 128 + t * 8];
#pragma unroll
        for (int i = 0; i < 8; ++i) acc[i] += (float)va[i] + (float)vb[i];
        j += 2;
    }
    if (j < s1) {
        int sA = eidx[j];
        half8_t va = *(const half8_t*)&T[(size_t)sA * 128 + t * 8];
#pragma unroll
        for (int i = 0; i < 8; ++i) acc[i] += (float)va[i];
    }

    float ri = rs_in[node];
    float ro = (MODE == 0) ? rs_out[node] : 1.0f;
    float4 bl = *(const float4*)&bias[t * 8];
    float4 bh = *(const float4*)&bias[t * 8 + 4];
    float bv[8] = {bl.x, bl.y, bl.z, bl.w, bh.x, bh.y, bh.z, bh.w};
    half8_t o;
#pragma unroll
    for (int i = 0; i < 8; ++i) {
        float x = fmaxf(fmaf(acc[i], ri, bv[i]), 0.f) * ro;
        o[i] = (_Float16)x;
    }
    *(half8_t*)&Xout[(size_t)node * 128 + t * 8] = o;
}

// out[n,16] = X3 @ Wc + bc   (X3 f16 already has relu/bias applied)
__global__ __launch_bounds__(256) void classifier_kernel(
    const _Float16* __restrict__ X, const float* __restrict__ Wc,
    const float* __restrict__ bout, float* __restrict__ out, int n)
{
    __shared__ float wl[128 * 16];       // 8 KB
    __shared__ _Float16 xs[16][128];     // 4 KB
    const int tid = threadIdx.x;
    const int row0 = blockIdx.x * 16;
#pragma unroll
    for (int i0 = 0; i0 < 2; ++i0) {
        int i = tid + i0 * 256;
        ((float4*)wl)[i] = ((const float4*)Wc)[i];
    }
    {
        int r = tid >> 4, c8 = (tid & 15) * 8;
        int row = row0 + r;
        float4 v = make_float4(0.f, 0.f, 0.f, 0.f);
        if (row < n) v = *(const float4*)&X[(size_t)row * 128 + c8];
        *(float4*)&xs[r][c8] = v;
    }
    __syncthreads();
    int c = tid & 15, r = tid >> 4;
    float acc = 0.f;
#pragma unroll 4
    for (int k = 0; k < 128; k += 2) {
        float x0 = (float)xs[r][k];
        float x1 = (float)xs[r][k + 1];
        acc = fmaf(x0, wl[k * 16 + c], acc);
        acc = fmaf(x1, wl[(k + 1) * 16 + c], acc);
    }
    int row = row0 + r;
    if (row < n) out[(size_t)row * 16 + c] = acc + bout[c];
}

extern "C" void kernel_launch(void* const* d_in, const int* in_sizes, int n_in,
                              void* d_out, int out_size, void* d_ws, size_t ws_size,
                              hipStream_t stream)
{
    const float* h   = (const float*)d_in[0];
    const int*   src = (const int*)d_in[1];
    const int*   dst = (const int*)d_in[2];
    const float* W1  = (const float*)d_in[3];
    const float* b1  = (const float*)d_in[4];
    const float* W2  = (const float*)d_in[5];
    const float* b2  = (const float*)d_in[6];
    const float* Wc  = (const float*)d_in[7];
    const float* bc  = (const float*)d_in[8];
    float* out = (float*)d_out;

    const int n = in_sizes[0] / 128;   // 100000
    const int E = in_sizes[1];         // 600000
    const int nb = (n + 255) / 256;    // 391 (<=1024)

    char* ws = (char*)d_ws;
    int*   cntO    = (int*)ws;                       // n
    int*   cntI    = cntO + n;                       // n
    int*   rank    = cntI + n;                       // E
    float* rs_out  = (float*)(rank + E);             // n
    float* rs_in   = rs_out + n;                     // n
    int*   starts  = (int*)(rs_in + n);              // n
    int*   bsum    = starts + n;                     // 1024
    int*   eidx    = bsum + 1024;                    // E
    _Float16* WB1  = (_Float16*)(eidx + E);          // 16384
    _Float16* WB2  = WB1 + 16384;                    // 16384
    size_t off = ((size_t)((char*)(WB2 + 16384) - ws) + 255) & ~(size_t)255;
    _Float16* bufA = (_Float16*)(ws + off);          // n*128 f16
    _Float16* bufB = bufA + (size_t)n * 128;         // n*128 f16

    hipMemsetAsync(cntO, 0, (size_t)2 * n * sizeof(int), stream);
    count_kernel<<<(E + 255) / 256, 256, 0, stream>>>(src, dst, cntO, cntI, rank, E);
    rs_kernel<<<(n + 255) / 256, 256, 0, stream>>>(cntO, cntI, rs_out, rs_in, n);
    scan1_kernel<<<nb, 256, 0, stream>>>(cntI, starts, bsum, n);
    scan2_kernel<<<1, 1024, 0, stream>>>(bsum, nb);
    scan3_kernel<<<nb, 256, 0, stream>>>(starts, bsum, n);
    fill_kernel<<<(E + 255) / 256, 256, 0, stream>>>(src, dst, rank, starts, eidx, E);
    wpack_kernel<<<128, 256, 0, stream>>>(W1, W2, WB1, WB2);

    int gblocks = (n + 127) / 128;   // 782
    int ablocks = (n + 15) / 16;     // gather: 4 waves/block x 4 nodes/wave

    // Layer 1
    gemm_mfma<0><<<gblocks, 256, 0, stream>>>(h, WB1, rs_out, bufA, n);
    gather_f16<0><<<ablocks, 256, 0, stream>>>(bufA, eidx, starts, rs_in, rs_out, b1, bufB, n, E);

    // Layer 2
    gemm_mfma<1><<<gblocks, 256, 0, stream>>>(bufB, WB2, rs_out, bufA, n);
    gather_f16<1><<<ablocks, 256, 0, stream>>>(bufA, eidx, starts, rs_in, rs_out, b2, bufB, n, E);

    // Classifier
    classifier_kernel<<<(n + 15) / 16, 256, 0, stream>>>(bufB, Wc, bc, out, n);
}